// Round 2
// baseline (1785.928 us; speedup 1.0000x reference)
//
#include <hip/hip_runtime.h>
#include <hip/hip_bf16.h>
#include <cstdint>
#include <cstddef>

#define NU   8000
#define NI   10000
#define NTOT 18000
#define G    4096
#define KP   18048   // k-dim padded to 282*64
#define KT   282

typedef __attribute__((ext_vector_type(8))) short bf16x8;
typedef __attribute__((ext_vector_type(4))) float f32x4;

__device__ __forceinline__ float bfu(unsigned short u){
  return __uint_as_float(((unsigned)u)<<16);
}
__device__ __forceinline__ unsigned short f2b(float f){
  __hip_bfloat16 h = __float2bfloat16(f);
  return __builtin_bit_cast(unsigned short, h);
}
__device__ __forceinline__ void async16(void* lds, const void* g){
  __builtin_amdgcn_global_load_lds((const __attribute__((address_space(1))) unsigned int*)g,
                                   (__attribute__((address_space(3))) unsigned int*)lds, 16, 0, 0);
}

// ---------------- K1: q/k/v projections, v rows, wsk = Ws @ k ----------------
__global__ __launch_bounds__(256) void k_proj(
    const float* __restrict__ feats,
    const float* uWq, const float* ubq,
    const float* uWk, const float* ubk,
    const float* uWv, const float* ubv,
    const float* uWs,
    const float* iWq, const float* ibq,
    const float* iWk, const float* ibk,
    const float* iWv, const float* ibv,
    const float* iWs,
    float* __restrict__ q, unsigned short* __restrict__ vrow, float* __restrict__ wsk)
{
  __shared__ unsigned short Wt[6*4096];   // transposed W (bf16): Wt[mat][j*64+d]
  __shared__ float bl[6*64];
  __shared__ float wacc[128];
  const float* mats[6]  = {uWq,uWk,uWv,iWq,iWk,iWv};
  const float* bias6[6] = {ubq,ubk,ubv,ibq,ibk,ibv};
  int t = threadIdx.x;
  for (int m=0;m<6;m++)
    for (int e=t; e<4096; e+=256){
      int dd = e>>6, jj = e&63;
      Wt[m*4096 + jj*64 + dd] = f2b(mats[m][e]);
    }
  for (int e=t; e<384; e+=256) bl[e] = bias6[e>>6][e&63];
  if (t<128) wacc[t]=0.f;
  __syncthreads();
  int wave=t>>6, lane=t&63;
  int gw = blockIdx.x*4+wave, nw = gridDim.x*4;
  float accU=0.f, accI=0.f;
  for (int n=gw; n<NTOT; n+=nw){
    int br = (n>=NU);
    const unsigned short* W = Wt + br*3*4096;
    const float* bb = bl + br*192;
    float x = feats[(size_t)n*64+lane];
    float qd=bb[lane], kd=bb[64+lane], vd=bb[128+lane];
    #pragma unroll 16
    for (int j=0;j<64;j++){
      float xj = __shfl(x, j, 64);
      qd += xj * bfu(W[       j*64+lane]);
      kd += xj * bfu(W[4096 + j*64+lane]);
      vd += xj * bfu(W[8192 + j*64+lane]);
    }
    q[(size_t)n*64+lane] = qd;
    vrow[(size_t)n*64+lane] = f2b(vd);
    float wsn = br ? iWs[n-NU] : uWs[n];
    if (br) accI += wsn*kd; else accU += wsn*kd;
  }
  atomicAdd(&wacc[lane], accU);
  atomicAdd(&wacc[64+lane], accI);
  __syncthreads();
  if (t<128) atomicAdd(&wsk[t], wacc[t]);
}

// ---------------- K2: r[n] = exp(q . wsk + bs) ----------------
__global__ __launch_bounds__(256) void k_score(const float* __restrict__ q, const float* __restrict__ wsk,
    const float* ubs, const float* ibs, float* __restrict__ r)
{
  __shared__ float wl[128];
  int t=threadIdx.x;
  if (t<128) wl[t]=wsk[t];
  __syncthreads();
  int n = blockIdx.x*256+t;
  if (n>=NTOT) return;
  int br = (n>=NU);
  const float* wk = wl + br*64;
  float s = br ? ibs[0] : ubs[0];
  const float* qr = q + (size_t)n*64;
  #pragma unroll
  for (int d=0;d<64;d++) s += qr[d]*wk[d];
  r[n] = expf(s);
}

// ---------------- K3: Zu/Zi column sums of H * r ----------------
__global__ __launch_bounds__(256) void k_colsum(const int* __restrict__ H, const float* __restrict__ r,
    float* __restrict__ Zu, float* __restrict__ Zi)
{
  int g = blockIdx.x*256 + threadIdx.x;
  int n0 = blockIdx.y*282;
  int n1 = n0+282; if (n1>NTOT) n1=NTOT;
  float zu=0.f, zi=0.f;
  for (int n=n0;n<n1;n++){
    float hv = (float)H[(size_t)n*G + g];
    float rv = r[n];
    if (n<NU) zu += hv*rv; else zi += hv*rv;
  }
  atomicAdd(&Zu[g], zu);
  atomicAdd(&Zi[g], zi);
}

// ---------------- K4: C = 1/Z, flags for all-masked columns ----------------
__global__ void k_prepC(const float* Zu, const float* Zi, float* Cu, float* Ci, int* Fu, int* Fi){
  int g = blockIdx.x*256+threadIdx.x;
  if (g>=G) return;
  float zu=Zu[g], zi=Zi[g];
  Cu[g] = zu>0.f ? 1.f/zu : 0.f; Fu[g] = zu>0.f ? 0 : 1;
  Ci[g] = zi>0.f ? 1.f/zi : 0.f; Fi[g] = zi>0.f ? 0 : 1;
}

// ---------------- K5: wT[g][n] = w[g,n] bf16, transposed build from H ----------------
__global__ __launch_bounds__(256) void k_buildWT(const int* __restrict__ H, const float* __restrict__ r,
    const float* __restrict__ Cu, const float* __restrict__ Ci,
    const int* __restrict__ Fu, const int* __restrict__ Fi, unsigned short* __restrict__ wT)
{
  __shared__ float tile[64][65];
  int n0 = blockIdx.x*64, g0 = blockIdx.y*64;
  int tc = threadIdx.x&63, tr = threadIdx.x>>6;
  #pragma unroll
  for (int i=0;i<16;i++){
    int rr = tr + i*4; int n = n0+rr;
    float val = 0.f;
    if (n < NTOT) val = (float)H[(size_t)n*G + g0+tc] * r[n];
    tile[rr][tc] = val;
  }
  __syncthreads();
  int br = (n0 >= NU);
  const float* C = br ? Ci : Cu;
  const int*  F = br ? Fi : Fu;
  float invN = br ? (1.f/(float)NI) : (1.f/(float)NU);
  #pragma unroll
  for (int i=0;i<16;i++){
    int gg = tr + i*4; int g = g0+gg;
    int n = n0 + tc;
    float wv;
    if (n >= NTOT)   wv = 0.f;
    else if (F[g])   wv = invN;
    else             wv = tile[tc][gg] * C[g];
    wT[(size_t)g*KP + n] = f2b(wv);
  }
}

// ---------------- K6: vt (128 x KP): branch-separated transposed V, zero-padded ----------------
__global__ __launch_bounds__(256) void k_buildVT(const unsigned short* __restrict__ vrow, unsigned short* __restrict__ vt){
  __shared__ unsigned short tile[64][65];
  int n0 = blockIdx.x*64;
  int tc = threadIdx.x&63, tr = threadIdx.x>>6;
  #pragma unroll
  for (int i=0;i<16;i++){
    int rr = tr+i*4; int n = n0+rr;
    tile[rr][tc] = (n<NTOT) ? vrow[(size_t)n*64+tc] : (unsigned short)0;
  }
  __syncthreads();
  int off = (n0>=NU) ? 64 : 0;
  int other = off ^ 64;
  #pragma unroll
  for (int i=0;i<16;i++){
    int dd = tr+i*4;
    vt[(size_t)(off  +dd)*KP + n0+tc] = tile[tc][dd];
    vt[(size_t)(other+dd)*KP + n0+tc] = 0;
  }
}

// ---------------- K7: bf16 GEMM  C(I,J) = A(I-rows) . B(J-rows)^T  (k-contig rows) ----------------
__global__ __launch_bounds__(256) void k_gemm_bt(
    const unsigned short* __restrict__ A, const unsigned short* __restrict__ B,
    float* __restrict__ Cf, unsigned short* __restrict__ Cb,
    float* __restrict__ diag, const float* __restrict__ rowScale,
    long ldA, long ldB, int ldc, int ktn, int doAtomic)
{
  __shared__ __align__(16) unsigned short As[128*64];
  __shared__ __align__(16) unsigned short Bs[128*64];
  int t=threadIdx.x, wave=t>>6, lane=t&63;
  int I=blockIdx.x, J=blockIdx.y;
  int kt0 = blockIdx.z*ktn;
  f32x4 acc[4][4];
  #pragma unroll
  for (int mi=0;mi<4;mi++){
    #pragma unroll
    for (int ni=0;ni<4;ni++){
      acc[mi][ni][0]=0.f; acc[mi][ni][1]=0.f; acc[mi][ni][2]=0.f; acc[mi][ni][3]=0.f;
    }
  }
  int rowOff = wave*8 + (lane>>3);
  long colOff = (long)(lane&7)*8;
  const unsigned short* Abase = A + (long)I*128*ldA + colOff;
  const unsigned short* Bbase = B + (long)J*128*ldB + colOff;
  unsigned short* AsW = As + wave*512;
  unsigned short* BsW = Bs + wave*512;
  for (int kt=kt0; kt<kt0+ktn; ++kt){
    long k0 = (long)kt*64;
    #pragma unroll
    for (int rr=0; rr<4; rr++){
      async16(AsW + rr*2048, Abase + (long)(rr*32 + rowOff)*ldA + k0);
      async16(BsW + rr*2048, Bbase + (long)(rr*32 + rowOff)*ldB + k0);
    }
    __syncthreads();
    #pragma unroll
    for (int kk=0; kk<2; kk++){
      bf16x8 af[4], bfv[4];
      #pragma unroll
      for (int mi=0;mi<4;mi++)
        af[mi] = *(const bf16x8*)(As + ((wave&1)*64 + mi*16 + (lane&15))*64 + kk*32 + (lane>>4)*8);
      #pragma unroll
      for (int ni=0;ni<4;ni++)
        bfv[ni] = *(const bf16x8*)(Bs + ((wave>>1)*64 + ni*16 + (lane&15))*64 + kk*32 + (lane>>4)*8);
      #pragma unroll
      for (int mi=0;mi<4;mi++){
        #pragma unroll
        for (int ni=0;ni<4;ni++)
          acc[mi][ni] = __builtin_amdgcn_mfma_f32_16x16x32_bf16(af[mi], bfv[ni], acc[mi][ni], 0,0,0);
      }
    }
    __syncthreads();
  }
  int m0=(wave&1)*64, n0=(wave>>1)*64;
  int cq = lane>>4, cl = lane&15;
  #pragma unroll
  for (int mi=0;mi<4;mi++){
    #pragma unroll
    for (int ni=0;ni<4;ni++){
      #pragma unroll
      for (int rg=0;rg<4;rg++){
        int gi = I*128 + m0 + mi*16 + cq*4 + rg;
        int hi = J*128 + n0 + ni*16 + cl;
        float v = acc[mi][ni][rg];
        if (rowScale) v *= rowScale[gi];
        if (doAtomic) atomicAdd(&Cf[(size_t)gi*ldc + hi], v);
        else {
          if (Cb) Cb[(size_t)gi*ldc + hi] = f2b(v);
          if (Cf) Cf[(size_t)gi*ldc + hi] = v;
          if (diag && I==J && gi==hi) diag[gi] = v;
        }
      }
    }
  }
}

// ---------------- K8: ninv = 1/sqrt(diag(wp)) ----------------
__global__ void k_normprep(const float* nrm2, float* ninv){
  int g=blockIdx.x*256+threadIdx.x;
  if (g<G) ninv[g] = 1.f/sqrtf(nrm2[g]);
}

// ---------------- K9: gfsT[d][g] = bf16(gf[g][d] * ninv[g]) ----------------
__global__ __launch_bounds__(256) void k_buildGfsT(const float* __restrict__ gf, const float* __restrict__ ninv,
                                                   unsigned short* __restrict__ gfsT){
  __shared__ float tile[64][65];
  int g0 = blockIdx.x*64, d0 = blockIdx.y*64;
  int tc=threadIdx.x&63, tr=threadIdx.x>>6;
  #pragma unroll
  for (int i=0;i<16;i++){
    int rr=tr+i*4;
    tile[rr][tc] = gf[(size_t)(g0+rr)*128 + d0+tc] * ninv[g0+rr];
  }
  __syncthreads();
  #pragma unroll
  for (int i=0;i<16;i++){
    int dd=tr+i*4;
    gfsT[(size_t)(d0+dd)*G + g0+tc] = f2b(tile[tc][dd]);
  }
}

// ---------------- K10: deg[h] = ninv[h] * sum_g wpb[h,g]*ninv[g] ----------------
__global__ __launch_bounds__(256) void k_deg(const unsigned short* __restrict__ wpb, const float* __restrict__ ninv,
                                             float* __restrict__ deg){
  __shared__ float red[4];
  int h=blockIdx.x, t=threadIdx.x;
  const unsigned short* row = wpb + (size_t)h*G;
  float s=0.f;
  for (int g=t; g<G; g+=256) s += bfu(row[g])*ninv[g];
  #pragma unroll
  for (int off=32; off>0; off>>=1) s += __shfl_down(s, off, 64);
  if ((t&63)==0) red[t>>6]=s;
  __syncthreads();
  if (t==0) deg[h] = (red[0]+red[1]+red[2]+red[3]) * ninv[h];
}

// ---------------- K11: agg = 0.8 gf + 0.2 msg/deg ; out = sigmoid(agg @ gW^T + gb) ----------------
__global__ __launch_bounds__(256) void k_final(const float* __restrict__ gf, const float* __restrict__ msg,
    const float* __restrict__ deg, const float* __restrict__ gW, const float* __restrict__ gb,
    float* __restrict__ out)
{
  __shared__ float Wl[64*129];
  __shared__ float aggL[4][128];
  __shared__ float gbL[64];
  int t=threadIdx.x;
  for (int e=t; e<8192; e+=256){ int o=e>>7, dd=e&127; Wl[o*129+dd] = gW[e]; }
  if (t<64) gbL[t] = gb[t];
  int g0 = blockIdx.x*4;
  for (int e=t; e<512; e+=256){
    int gl=e>>7, dd=e&127; int g=g0+gl;
    float dv = deg[g];
    float hn = dv>0.f ? msg[(size_t)g*128+dd]/dv : 0.f;
    aggL[gl][dd] = 0.8f*gf[(size_t)g*128+dd] + 0.2f*hn;
  }
  __syncthreads();
  int gl = t>>6, o = t&63;
  float s = gbL[o];
  #pragma unroll
  for (int dd=0; dd<128; dd++) s += aggL[gl][dd]*Wl[o*129+dd];
  out[(size_t)(g0+gl)*64 + o] = 1.f/(1.f+expf(-s));
}

extern "C" void kernel_launch(void* const* d_in, const int* in_sizes, int n_in,
                              void* d_out, int out_size, void* d_ws, size_t ws_size,
                              hipStream_t stream)
{
  (void)in_sizes; (void)n_in; (void)out_size; (void)ws_size;
  const int* H = (const int*)d_in[0];
  const float* feats = (const float*)d_in[1];
  const float* uWq=(const float*)d_in[3];
  const float* ubq=(const float*)d_in[4];
  const float* uWk=(const float*)d_in[5];
  const float* ubk=(const float*)d_in[6];
  const float* uWv=(const float*)d_in[7];
  const float* ubv=(const float*)d_in[8];
  const float* uWs=(const float*)d_in[9];
  const float* ubs=(const float*)d_in[10];
  const float* iWq=(const float*)d_in[11];
  const float* ibq=(const float*)d_in[12];
  const float* iWk=(const float*)d_in[13];
  const float* ibk=(const float*)d_in[14];
  const float* iWv=(const float*)d_in[15];
  const float* ibv=(const float*)d_in[16];
  const float* iWs=(const float*)d_in[17];
  const float* ibs=(const float*)d_in[18];
  const float* gW =(const float*)d_in[19];
  const float* gb =(const float*)d_in[20];
  float* out = (float*)d_out;

  char* p = (char*)d_ws;
  auto alloc=[&](size_t b)->void*{ void* r=(void*)p; p += (b+255)&~(size_t)255; return r; };
  unsigned short* wT  = (unsigned short*)alloc((size_t)G*KP*2);
  unsigned short* vt  = (unsigned short*)alloc((size_t)128*KP*2);
  unsigned short* wpb = (unsigned short*)alloc((size_t)G*G*2);
  float* q    = (float*)alloc((size_t)NTOT*64*4);
  unsigned short* vrow=(unsigned short*)alloc((size_t)NTOT*64*2);
  float* r    = (float*)alloc((size_t)NTOT*4);
  float* Zu   = (float*)alloc(G*4);
  float* Zi   = (float*)alloc(G*4);
  float* Cu   = (float*)alloc(G*4);
  float* Ci   = (float*)alloc(G*4);
  int*   Fu   = (int*)alloc(G*4);
  int*   Fi   = (int*)alloc(G*4);
  float* wsk  = (float*)alloc(128*4);
  float* gf   = (float*)alloc((size_t)G*128*4);
  unsigned short* gfsT = (unsigned short*)alloc((size_t)128*G*2);
  float* nrm2 = (float*)alloc(G*4);
  float* ninv = (float*)alloc(G*4);
  float* msg  = (float*)alloc((size_t)G*128*4);
  float* deg  = (float*)alloc(G*4);

  hipMemsetAsync(wsk, 0, 128*4, stream);
  hipMemsetAsync(Zu,  0, G*4, stream);
  hipMemsetAsync(Zi,  0, G*4, stream);
  hipMemsetAsync(gf,  0, (size_t)G*128*4, stream);
  hipMemsetAsync(msg, 0, (size_t)G*128*4, stream);

  k_proj<<<128,256,0,stream>>>(feats, uWq,ubq,uWk,ubk,uWv,ubv,uWs,
                               iWq,ibq,iWk,ibk,iWv,ibv,iWs, q, vrow, wsk);
  k_score<<<(NTOT+255)/256,256,0,stream>>>(q, wsk, ubs, ibs, r);
  k_colsum<<<dim3(16,64),256,0,stream>>>(H, r, Zu, Zi);
  k_prepC<<<16,256,0,stream>>>(Zu,Zi,Cu,Ci,Fu,Fi);
  k_buildWT<<<dim3(KT,64),256,0,stream>>>(H, r, Cu, Ci, Fu, Fi, wT);
  k_buildVT<<<KT,256,0,stream>>>(vrow, vt);
  // group_feats = wT . vt^T   (split-K, atomic f32)
  k_gemm_bt<<<dim3(32,1,6),256,0,stream>>>(wT, vt, gf, nullptr, nullptr, nullptr,
                                           (long)KP, (long)KP, 128, 47, 1);
  // wp = wT . wT^T  -> bf16 wpb + f32 diagonal
  k_gemm_bt<<<dim3(32,32,1),256,0,stream>>>(wT, wT, nullptr, wpb, nrm2, nullptr,
                                            (long)KP, (long)KP, G, KT, 0);
  k_normprep<<<16,256,0,stream>>>(nrm2, ninv);
  k_buildGfsT<<<dim3(64,2),256,0,stream>>>(gf, ninv, gfsT);
  // msg = D . wp . (D . gf)   (split-K, atomic, row-scaled by ninv)
  k_gemm_bt<<<dim3(32,1,4),256,0,stream>>>(wpb, gfsT, msg, nullptr, nullptr, ninv,
                                           (long)G, (long)G, 128, 16, 1);
  k_deg<<<G,256,0,stream>>>(wpb, ninv, deg);
  k_final<<<G/4,256,0,stream>>>(gf, msg, deg, gW, gb, out);
}

// Round 3
// 1595.231 us; speedup vs baseline: 1.1195x; 1.1195x over previous
//
#include <hip/hip_runtime.h>
#include <hip/hip_bf16.h>
#include <cstdint>
#include <cstddef>

#define NU   8000
#define NI   10000
#define NTOT 18000
#define G    4096
#define KP   18048   // k-dim padded to 282*64
#define KT   282

typedef __attribute__((ext_vector_type(8))) short bf16x8;
typedef __attribute__((ext_vector_type(4))) float f32x4;

__device__ __forceinline__ float bfu(unsigned short u){
  return __uint_as_float(((unsigned)u)<<16);
}
__device__ __forceinline__ unsigned short f2b(float f){
  __hip_bfloat16 h = __float2bfloat16(f);
  return __builtin_bit_cast(unsigned short, h);
}
__device__ __forceinline__ void async16(void* lds, const void* g){
  __builtin_amdgcn_global_load_lds((const __attribute__((address_space(1))) unsigned int*)g,
                                   (__attribute__((address_space(3))) unsigned int*)lds, 16, 0, 0);
}

// ---------------- K1: q/k/v projections, v rows, wsk = Ws @ k ----------------
__global__ __launch_bounds__(256) void k_proj(
    const float* __restrict__ feats,
    const float* uWq, const float* ubq,
    const float* uWk, const float* ubk,
    const float* uWv, const float* ubv,
    const float* uWs,
    const float* iWq, const float* ibq,
    const float* iWk, const float* ibk,
    const float* iWv, const float* ibv,
    const float* iWs,
    float* __restrict__ q, unsigned short* __restrict__ vrow, float* __restrict__ wsk)
{
  __shared__ unsigned short Wt[6*4096];   // transposed W (bf16): Wt[mat][j*64+d]
  __shared__ float bl[6*64];
  __shared__ float wacc[128];
  const float* mats[6]  = {uWq,uWk,uWv,iWq,iWk,iWv};
  const float* bias6[6] = {ubq,ubk,ubv,ibq,ibk,ibv};
  int t = threadIdx.x;
  for (int m=0;m<6;m++)
    for (int e=t; e<4096; e+=256){
      int dd = e>>6, jj = e&63;
      Wt[m*4096 + jj*64 + dd] = f2b(mats[m][e]);
    }
  for (int e=t; e<384; e+=256) bl[e] = bias6[e>>6][e&63];
  if (t<128) wacc[t]=0.f;
  __syncthreads();
  int wave=t>>6, lane=t&63;
  int gw = blockIdx.x*4+wave, nw = gridDim.x*4;
  float accU=0.f, accI=0.f;
  for (int n=gw; n<NTOT; n+=nw){
    int br = (n>=NU);
    const unsigned short* W = Wt + br*3*4096;
    const float* bb = bl + br*192;
    float x = feats[(size_t)n*64+lane];
    float qd=bb[lane], kd=bb[64+lane], vd=bb[128+lane];
    #pragma unroll 16
    for (int j=0;j<64;j++){
      float xj = __shfl(x, j, 64);
      qd += xj * bfu(W[       j*64+lane]);
      kd += xj * bfu(W[4096 + j*64+lane]);
      vd += xj * bfu(W[8192 + j*64+lane]);
    }
    q[(size_t)n*64+lane] = qd;
    vrow[(size_t)n*64+lane] = f2b(vd);
    float wsn = br ? iWs[n-NU] : uWs[n];
    if (br) accI += wsn*kd; else accU += wsn*kd;
  }
  atomicAdd(&wacc[lane], accU);
  atomicAdd(&wacc[64+lane], accI);
  __syncthreads();
  if (t<128) atomicAdd(&wsk[t], wacc[t]);
}

// ---------------- K2: r[n] = exp(q . wsk + bs) ----------------
__global__ __launch_bounds__(256) void k_score(const float* __restrict__ q, const float* __restrict__ wsk,
    const float* ubs, const float* ibs, float* __restrict__ r)
{
  __shared__ float wl[128];
  int t=threadIdx.x;
  if (t<128) wl[t]=wsk[t];
  __syncthreads();
  int n = blockIdx.x*256+t;
  if (n>=NTOT) return;
  int br = (n>=NU);
  const float* wk = wl + br*64;
  float s = br ? ibs[0] : ubs[0];
  const float* qr = q + (size_t)n*64;
  #pragma unroll
  for (int d=0;d<64;d++) s += qr[d]*wk[d];
  r[n] = expf(s);
}

// ---------------- K3: Zu/Zi column sums of H * r ----------------
__global__ __launch_bounds__(256) void k_colsum(const int* __restrict__ H, const float* __restrict__ r,
    float* __restrict__ Zu, float* __restrict__ Zi)
{
  int g = blockIdx.x*256 + threadIdx.x;
  int n0 = blockIdx.y*282;
  int n1 = n0+282; if (n1>NTOT) n1=NTOT;
  float zu=0.f, zi=0.f;
  for (int n=n0;n<n1;n++){
    float hv = (float)H[(size_t)n*G + g];
    float rv = r[n];
    if (n<NU) zu += hv*rv; else zi += hv*rv;
  }
  atomicAdd(&Zu[g], zu);
  atomicAdd(&Zi[g], zi);
}

// ---------------- K4: C = 1/Z, flags for all-masked columns ----------------
__global__ void k_prepC(const float* Zu, const float* Zi, float* Cu, float* Ci, int* Fu, int* Fi){
  int g = blockIdx.x*256+threadIdx.x;
  if (g>=G) return;
  float zu=Zu[g], zi=Zi[g];
  Cu[g] = zu>0.f ? 1.f/zu : 0.f; Fu[g] = zu>0.f ? 0 : 1;
  Ci[g] = zi>0.f ? 1.f/zi : 0.f; Fi[g] = zi>0.f ? 0 : 1;
}

// ---------------- K5: wT[g][n] = w[g,n] bf16, transposed build from H ----------------
__global__ __launch_bounds__(256) void k_buildWT(const int* __restrict__ H, const float* __restrict__ r,
    const float* __restrict__ Cu, const float* __restrict__ Ci,
    const int* __restrict__ Fu, const int* __restrict__ Fi, unsigned short* __restrict__ wT)
{
  __shared__ float tile[64][65];
  int n0 = blockIdx.x*64, g0 = blockIdx.y*64;
  int tc = threadIdx.x&63, tr = threadIdx.x>>6;
  #pragma unroll
  for (int i=0;i<16;i++){
    int rr = tr + i*4; int n = n0+rr;
    float val = 0.f;
    if (n < NTOT) val = (float)H[(size_t)n*G + g0+tc] * r[n];
    tile[rr][tc] = val;
  }
  __syncthreads();
  int br = (n0 >= NU);
  const float* C = br ? Ci : Cu;
  const int*  F = br ? Fi : Fu;
  float invN = br ? (1.f/(float)NI) : (1.f/(float)NU);
  #pragma unroll
  for (int i=0;i<16;i++){
    int gg = tr + i*4; int g = g0+gg;
    int n = n0 + tc;
    float wv;
    if (n >= NTOT)   wv = 0.f;
    else if (F[g])   wv = invN;
    else             wv = tile[tc][gg] * C[g];
    wT[(size_t)g*KP + n] = f2b(wv);
  }
}

// ---------------- K6: vt (128 x KP): branch-separated transposed V, zero-padded ----------------
__global__ __launch_bounds__(256) void k_buildVT(const unsigned short* __restrict__ vrow, unsigned short* __restrict__ vt){
  __shared__ unsigned short tile[64][65];
  int n0 = blockIdx.x*64;
  int tc = threadIdx.x&63, tr = threadIdx.x>>6;
  #pragma unroll
  for (int i=0;i<16;i++){
    int rr = tr+i*4; int n = n0+rr;
    tile[rr][tc] = (n<NTOT) ? vrow[(size_t)n*64+tc] : (unsigned short)0;
  }
  __syncthreads();
  int off = (n0>=NU) ? 64 : 0;
  int other = off ^ 64;
  #pragma unroll
  for (int i=0;i<16;i++){
    int dd = tr+i*4;
    vt[(size_t)(off  +dd)*KP + n0+tc] = tile[tc][dd];
    vt[(size_t)(other+dd)*KP + n0+tc] = 0;
  }
}

// ---------------- K7: generic bf16 GEMM  C(I,J) = A . B^T, swizzled LDS ----------------
__global__ __launch_bounds__(256) void k_gemm_bt(
    const unsigned short* __restrict__ A, const unsigned short* __restrict__ B,
    float* __restrict__ Cf, const float* __restrict__ rowScale,
    long ldA, long ldB, int ldc, int ktn)
{
  __shared__ __align__(16) unsigned short As[128*64];
  __shared__ __align__(16) unsigned short Bs[128*64];
  int t=threadIdx.x, wave=t>>6, lane=t&63;
  int I=blockIdx.x, J=blockIdx.y;
  int kt0 = blockIdx.z*ktn;
  f32x4 acc[4][4];
  #pragma unroll
  for (int mi=0;mi<4;mi++)
    #pragma unroll
    for (int ni=0;ni<4;ni++){
      acc[mi][ni][0]=0.f; acc[mi][ni][1]=0.f; acc[mi][ni][2]=0.f; acc[mi][ni][3]=0.f;
    }
  int l7 = lane&7, q4 = lane>>4, cl15 = lane&15;
  int rowOff = wave*8 + (lane>>3);
  int cchunk = (lane&7) ^ ((lane>>3)&7);       // swizzled global chunk for staging
  const unsigned short* Abase = A + (long)I*128*ldA + (long)cchunk*8;
  const unsigned short* Bbase = B + (long)J*128*ldB + (long)cchunk*8;
  unsigned short* AsW = As + wave*512;
  unsigned short* BsW = Bs + wave*512;
  int mrow0 = (wave&1)*64, nrow0 = (wave>>1)*64;
  for (int kt=kt0; kt<kt0+ktn; ++kt){
    long k0 = (long)kt*64;
    #pragma unroll
    for (int rr=0; rr<4; rr++){
      async16(AsW + rr*2048, Abase + (long)(rr*32 + rowOff)*ldA + k0);
      async16(BsW + rr*2048, Bbase + (long)(rr*32 + rowOff)*ldB + k0);
    }
    __syncthreads();
    #pragma unroll
    for (int kk=0; kk<2; kk++){
      int xoff = ((kk*4 + q4) ^ l7)*8;         // swizzled chunk on read
      bf16x8 af[4], bfv[4];
      #pragma unroll
      for (int mi=0;mi<4;mi++)
        af[mi] = *(const bf16x8*)(As + (mrow0 + mi*16 + cl15)*64 + xoff);
      #pragma unroll
      for (int ni=0;ni<4;ni++)
        bfv[ni] = *(const bf16x8*)(Bs + (nrow0 + ni*16 + cl15)*64 + xoff);
      #pragma unroll
      for (int mi=0;mi<4;mi++)
        #pragma unroll
        for (int ni=0;ni<4;ni++)
          acc[mi][ni] = __builtin_amdgcn_mfma_f32_16x16x32_bf16(af[mi], bfv[ni], acc[mi][ni], 0,0,0);
    }
    __syncthreads();
  }
  int cq = lane>>4, cl = lane&15;
  #pragma unroll
  for (int mi=0;mi<4;mi++)
    #pragma unroll
    for (int ni=0;ni<4;ni++)
      #pragma unroll
      for (int rg=0;rg<4;rg++){
        int gi = I*128 + mrow0 + mi*16 + cq*4 + rg;
        int hi = J*128 + nrow0 + ni*16 + cl;
        float v = acc[mi][ni][rg];
        if (rowScale) v *= rowScale[gi];
        atomicAdd(&Cf[(size_t)gi*ldc + hi], v);
      }
}

// ---------------- K7b: triangular syrk  wp = wT . wT^T  (bf16 out + mirror + diag) ----------------
__global__ __launch_bounds__(256) void k_syrk(
    const unsigned short* __restrict__ A,
    unsigned short* __restrict__ Cb, float* __restrict__ diag)
{
  __shared__ __align__(16) unsigned short smem[2*128*64];
  unsigned short* As = smem;
  unsigned short* Bs = smem + 128*64;
  int t=threadIdx.x, wave=t>>6, lane=t&63;
  // map linear z -> lower-triangle (r,c), c<=r ; I=c, J=r
  int z = blockIdx.x;
  int rr_ = (int)((sqrtf(8.f*z+1.f)-1.f)*0.5f);
  while ((rr_+1)*(rr_+2)/2 <= z) ++rr_;
  while (rr_*(rr_+1)/2 > z) --rr_;
  int I = z - rr_*(rr_+1)/2;
  int J = rr_;
  f32x4 acc[4][4];
  #pragma unroll
  for (int mi=0;mi<4;mi++)
    #pragma unroll
    for (int ni=0;ni<4;ni++){
      acc[mi][ni][0]=0.f; acc[mi][ni][1]=0.f; acc[mi][ni][2]=0.f; acc[mi][ni][3]=0.f;
    }
  int l7 = lane&7, q4 = lane>>4, cl15 = lane&15;
  int rowOff = wave*8 + (lane>>3);
  int cchunk = (lane&7) ^ ((lane>>3)&7);
  const unsigned short* Abase = A + (long)I*128*KP + (long)cchunk*8;
  const unsigned short* Bbase = A + (long)J*128*KP + (long)cchunk*8;
  unsigned short* AsW = As + wave*512;
  unsigned short* BsW = Bs + wave*512;
  int mrow0 = (wave&1)*64, nrow0 = (wave>>1)*64;
  for (int kt=0; kt<KT; ++kt){
    long k0 = (long)kt*64;
    #pragma unroll
    for (int rr=0; rr<4; rr++){
      async16(AsW + rr*2048, Abase + (long)(rr*32 + rowOff)*KP + k0);
      async16(BsW + rr*2048, Bbase + (long)(rr*32 + rowOff)*KP + k0);
    }
    __syncthreads();
    #pragma unroll
    for (int kk=0; kk<2; kk++){
      int xoff = ((kk*4 + q4) ^ l7)*8;
      bf16x8 af[4], bfv[4];
      #pragma unroll
      for (int mi=0;mi<4;mi++)
        af[mi] = *(const bf16x8*)(As + (mrow0 + mi*16 + cl15)*64 + xoff);
      #pragma unroll
      for (int ni=0;ni<4;ni++)
        bfv[ni] = *(const bf16x8*)(Bs + (nrow0 + ni*16 + cl15)*64 + xoff);
      #pragma unroll
      for (int mi=0;mi<4;mi++)
        #pragma unroll
        for (int ni=0;ni<4;ni++)
          acc[mi][ni] = __builtin_amdgcn_mfma_f32_16x16x32_bf16(af[mi], bfv[ni], acc[mi][ni], 0,0,0);
    }
    __syncthreads();
  }
  int cq = lane>>4, cl = lane&15;
  // direct tile write (rows = I-tile, cols = J-tile) + diag
  #pragma unroll
  for (int mi=0;mi<4;mi++)
    #pragma unroll
    for (int ni=0;ni<4;ni++)
      #pragma unroll
      for (int rg=0;rg<4;rg++){
        int gi = I*128 + mrow0 + mi*16 + cq*4 + rg;
        int hi = J*128 + nrow0 + ni*16 + cl;
        float v = acc[mi][ni][rg];
        Cb[(size_t)gi*G + hi] = f2b(v);
        if (I==J && gi==hi) diag[gi] = v;
      }
  if (I==J) return;
  // mirror tile: stage transposed bf16 into LDS (chunk-swizzled), then coalesced write
  unsigned short* Ct = smem;  // 128 rows x 128 shorts = 32 KB
  #pragma unroll
  for (int mi=0;mi<4;mi++)
    #pragma unroll
    for (int ni=0;ni<4;ni++)
      #pragma unroll
      for (int rg=0;rg<4;rg++){
        int row = nrow0 + ni*16 + cl;              // hi local
        int mcol = mrow0 + mi*16 + cq*4 + rg;      // gi local
        int cs = (mcol & 7) | ((((mcol>>3) ^ (row&7)) & 15) << 3);
        Ct[row*128 + cs] = f2b(acc[mi][ni][rg]);
      }
  __syncthreads();
  // write rows hi = J*128+row, cols gi = I*128.. (uint2 = 4 shorts)
  const uint2* Ct2 = (const uint2*)Ct;
  uint2* dst = (uint2*)Cb;
  for (int i=t; i<128*32; i+=256){
    int row = i>>5, c2 = i&31;           // c2: uint2 index within row (8B = 4 shorts)
    int chunk = c2>>1;                   // 16B chunk index 0..15
    int pchunk = chunk ^ (row&7);
    uint2 val = Ct2[row*32 + pchunk*2 + (c2&1)];
    dst[(size_t)(J*128+row)*1024 + I*32 + c2] = val;
  }
}

// ---------------- K8: ninv = 1/sqrt(diag(wp)) ----------------
__global__ void k_normprep(const float* nrm2, float* ninv){
  int g=blockIdx.x*256+threadIdx.x;
  if (g<G) ninv[g] = 1.f/sqrtf(nrm2[g]);
}

// ---------------- K9: gfsT[d][g] = bf16(gf[g][d] * ninv[g]) ----------------
__global__ __launch_bounds__(256) void k_buildGfsT(const float* __restrict__ gf, const float* __restrict__ ninv,
                                                   unsigned short* __restrict__ gfsT){
  __shared__ float tile[64][65];
  int g0 = blockIdx.x*64, d0 = blockIdx.y*64;
  int tc=threadIdx.x&63, tr=threadIdx.x>>6;
  #pragma unroll
  for (int i=0;i<16;i++){
    int rr=tr+i*4;
    tile[rr][tc] = gf[(size_t)(g0+rr)*128 + d0+tc] * ninv[g0+rr];
  }
  __syncthreads();
  #pragma unroll
  for (int i=0;i<16;i++){
    int dd=tr+i*4;
    gfsT[(size_t)(d0+dd)*G + g0+tc] = f2b(tile[tc][dd]);
  }
}

// ---------------- K10: deg[h] = ninv[h] * sum_g wpb[h,g]*ninv[g] ----------------
__global__ __launch_bounds__(256) void k_deg(const unsigned short* __restrict__ wpb, const float* __restrict__ ninv,
                                             float* __restrict__ deg){
  __shared__ float red[4];
  int h=blockIdx.x, t=threadIdx.x;
  const unsigned short* row = wpb + (size_t)h*G;
  float s=0.f;
  for (int g=t; g<G; g+=256) s += bfu(row[g])*ninv[g];
  #pragma unroll
  for (int off=32; off>0; off>>=1) s += __shfl_down(s, off, 64);
  if ((t&63)==0) red[t>>6]=s;
  __syncthreads();
  if (t==0) deg[h] = (red[0]+red[1]+red[2]+red[3]) * ninv[h];
}

// ---------------- K11: agg = 0.8 gf + 0.2 msg/deg ; out = sigmoid(agg @ gW^T + gb) ----------------
__global__ __launch_bounds__(256) void k_final(const float* __restrict__ gf, const float* __restrict__ msg,
    const float* __restrict__ deg, const float* __restrict__ gW, const float* __restrict__ gb,
    float* __restrict__ out)
{
  __shared__ float Wl[64*129];
  __shared__ float aggL[4][128];
  __shared__ float gbL[64];
  int t=threadIdx.x;
  for (int e=t; e<8192; e+=256){ int o=e>>7, dd=e&127; Wl[o*129+dd] = gW[e]; }
  if (t<64) gbL[t] = gb[t];
  int g0 = blockIdx.x*4;
  for (int e=t; e<512; e+=256){
    int gl=e>>7, dd=e&127; int g=g0+gl;
    float dv = deg[g];
    float hn = dv>0.f ? msg[(size_t)g*128+dd]/dv : 0.f;
    aggL[gl][dd] = 0.8f*gf[(size_t)g*128+dd] + 0.2f*hn;
  }
  __syncthreads();
  int gl = t>>6, o = t&63;
  float s = gbL[o];
  #pragma unroll
  for (int dd=0; dd<128; dd++) s += aggL[gl][dd]*Wl[o*129+dd];
  out[(size_t)(g0+gl)*64 + o] = 1.f/(1.f+expf(-s));
}

extern "C" void kernel_launch(void* const* d_in, const int* in_sizes, int n_in,
                              void* d_out, int out_size, void* d_ws, size_t ws_size,
                              hipStream_t stream)
{
  (void)in_sizes; (void)n_in; (void)out_size; (void)ws_size;
  const int* H = (const int*)d_in[0];
  const float* feats = (const float*)d_in[1];
  const float* uWq=(const float*)d_in[3];
  const float* ubq=(const float*)d_in[4];
  const float* uWk=(const float*)d_in[5];
  const float* ubk=(const float*)d_in[6];
  const float* uWv=(const float*)d_in[7];
  const float* ubv=(const float*)d_in[8];
  const float* uWs=(const float*)d_in[9];
  const float* ubs=(const float*)d_in[10];
  const float* iWq=(const float*)d_in[11];
  const float* ibq=(const float*)d_in[12];
  const float* iWk=(const float*)d_in[13];
  const float* ibk=(const float*)d_in[14];
  const float* iWv=(const float*)d_in[15];
  const float* ibv=(const float*)d_in[16];
  const float* iWs=(const float*)d_in[17];
  const float* ibs=(const float*)d_in[18];
  const float* gW =(const float*)d_in[19];
  const float* gb =(const float*)d_in[20];
  float* out = (float*)d_out;

  char* p = (char*)d_ws;
  auto alloc=[&](size_t b)->void*{ void* r=(void*)p; p += (b+255)&~(size_t)255; return r; };
  unsigned short* wT  = (unsigned short*)alloc((size_t)G*KP*2);
  unsigned short* vt  = (unsigned short*)alloc((size_t)128*KP*2);
  unsigned short* wpb = (unsigned short*)alloc((size_t)G*G*2);
  float* q    = (float*)alloc((size_t)NTOT*64*4);
  unsigned short* vrow=(unsigned short*)alloc((size_t)NTOT*64*2);
  float* r    = (float*)alloc((size_t)NTOT*4);
  float* Zu   = (float*)alloc(G*4);
  float* Zi   = (float*)alloc(G*4);
  float* Cu   = (float*)alloc(G*4);
  float* Ci   = (float*)alloc(G*4);
  int*   Fu   = (int*)alloc(G*4);
  int*   Fi   = (int*)alloc(G*4);
  float* wsk  = (float*)alloc(128*4);
  float* gf   = (float*)alloc((size_t)G*128*4);
  unsigned short* gfsT = (unsigned short*)alloc((size_t)128*G*2);
  float* nrm2 = (float*)alloc(G*4);
  float* ninv = (float*)alloc(G*4);
  float* msg  = (float*)alloc((size_t)G*128*4);
  float* deg  = (float*)alloc(G*4);

  hipMemsetAsync(wsk, 0, 128*4, stream);
  hipMemsetAsync(Zu,  0, G*4, stream);
  hipMemsetAsync(Zi,  0, G*4, stream);
  hipMemsetAsync(gf,  0, (size_t)G*128*4, stream);
  hipMemsetAsync(msg, 0, (size_t)G*128*4, stream);

  k_proj<<<128,256,0,stream>>>(feats, uWq,ubq,uWk,ubk,uWv,ubv,uWs,
                               iWq,ibq,iWk,ibk,iWv,ibv,iWs, q, vrow, wsk);
  k_score<<<(NTOT+255)/256,256,0,stream>>>(q, wsk, ubs, ibs, r);
  k_colsum<<<dim3(16,64),256,0,stream>>>(H, r, Zu, Zi);
  k_prepC<<<16,256,0,stream>>>(Zu,Zi,Cu,Ci,Fu,Fi);
  k_buildWT<<<dim3(KT,64),256,0,stream>>>(H, r, Cu, Ci, Fu, Fi, wT);
  k_buildVT<<<KT,256,0,stream>>>(vrow, vt);
  // group_feats = wT . vt^T   (split-K, atomic f32)
  k_gemm_bt<<<dim3(32,1,6),256,0,stream>>>(wT, vt, gf, nullptr, (long)KP, (long)KP, 128, 47);
  // wp = wT . wT^T  -> bf16 wpb (triangular + mirror) + f32 diagonal
  k_syrk<<<528,256,0,stream>>>(wT, wpb, nrm2);
  k_normprep<<<16,256,0,stream>>>(nrm2, ninv);
  k_buildGfsT<<<dim3(64,2),256,0,stream>>>(gf, ninv, gfsT);
  // msg = D . wp . (D . gf)   (split-K, atomic, row-scaled by ninv)
  k_gemm_bt<<<dim3(32,1,4),256,0,stream>>>(wpb, gfsT, msg, ninv, (long)G, (long)G, 128, 16);
  k_deg<<<G,256,0,stream>>>(wpb, ninv, deg);
  k_final<<<G/4,256,0,stream>>>(gf, msg, deg, gW, gb, out);
}

// Round 4
// 1290.046 us; speedup vs baseline: 1.3844x; 1.2366x over previous
//
#include <hip/hip_runtime.h>
#include <hip/hip_bf16.h>
#include <cstdint>
#include <cstddef>

#define NU   8000
#define NI   10000
#define NTOT 18000
#define G    4096
#define KP   18048   // k-dim padded to 282*64
#define KT   282

typedef __attribute__((ext_vector_type(8))) short bf16x8;
typedef __attribute__((ext_vector_type(4))) float f32x4;

__device__ __forceinline__ float bfu(unsigned short u){
  return __uint_as_float(((unsigned)u)<<16);
}
__device__ __forceinline__ unsigned short f2b(float f){
  __hip_bfloat16 h = __float2bfloat16(f);
  return __builtin_bit_cast(unsigned short, h);
}
__device__ __forceinline__ void async16(void* lds, const void* g){
  __builtin_amdgcn_global_load_lds((const __attribute__((address_space(1))) unsigned int*)g,
                                   (__attribute__((address_space(3))) unsigned int*)lds, 16, 0, 0);
}

// ---------------- K1: q/k/v projections, v rows, wsk = Ws @ k ----------------
__global__ __launch_bounds__(256) void k_proj(
    const float* __restrict__ feats,
    const float* uWq, const float* ubq,
    const float* uWk, const float* ubk,
    const float* uWv, const float* ubv,
    const float* uWs,
    const float* iWq, const float* ibq,
    const float* iWk, const float* ibk,
    const float* iWv, const float* ibv,
    const float* iWs,
    float* __restrict__ q, unsigned short* __restrict__ vrow, float* __restrict__ wsk)
{
  __shared__ unsigned short Wt[6*4096];   // transposed W (bf16): Wt[mat][j*64+d]
  __shared__ float bl[6*64];
  __shared__ float wacc[128];
  const float* mats[6]  = {uWq,uWk,uWv,iWq,iWk,iWv};
  const float* bias6[6] = {ubq,ubk,ubv,ibq,ibk,ibv};
  int t = threadIdx.x;
  for (int m=0;m<6;m++)
    for (int e=t; e<4096; e+=256){
      int dd = e>>6, jj = e&63;
      Wt[m*4096 + jj*64 + dd] = f2b(mats[m][e]);
    }
  for (int e=t; e<384; e+=256) bl[e] = bias6[e>>6][e&63];
  if (t<128) wacc[t]=0.f;
  __syncthreads();
  int wave=t>>6, lane=t&63;
  int gw = blockIdx.x*4+wave, nw = gridDim.x*4;
  float accU=0.f, accI=0.f;
  for (int n=gw; n<NTOT; n+=nw){
    int br = (n>=NU);
    const unsigned short* W = Wt + br*3*4096;
    const float* bb = bl + br*192;
    float x = feats[(size_t)n*64+lane];
    float qd=bb[lane], kd=bb[64+lane], vd=bb[128+lane];
    #pragma unroll 16
    for (int j=0;j<64;j++){
      float xj = __shfl(x, j, 64);
      qd += xj * bfu(W[       j*64+lane]);
      kd += xj * bfu(W[4096 + j*64+lane]);
      vd += xj * bfu(W[8192 + j*64+lane]);
    }
    q[(size_t)n*64+lane] = qd;
    vrow[(size_t)n*64+lane] = f2b(vd);
    float wsn = br ? iWs[n-NU] : uWs[n];
    if (br) accI += wsn*kd; else accU += wsn*kd;
  }
  atomicAdd(&wacc[lane], accU);
  atomicAdd(&wacc[64+lane], accI);
  __syncthreads();
  if (t<128) atomicAdd(&wsk[t], wacc[t]);
}

// ---------------- K2: r[n] = exp(q . wsk + bs) ----------------
__global__ __launch_bounds__(256) void k_score(const float* __restrict__ q, const float* __restrict__ wsk,
    const float* ubs, const float* ibs, float* __restrict__ r)
{
  __shared__ float wl[128];
  int t=threadIdx.x;
  if (t<128) wl[t]=wsk[t];
  __syncthreads();
  int n = blockIdx.x*256+t;
  if (n>=NTOT) return;
  int br = (n>=NU);
  const float* wk = wl + br*64;
  float s = br ? ibs[0] : ubs[0];
  const float* qr = q + (size_t)n*64;
  #pragma unroll
  for (int d=0;d<64;d++) s += qr[d]*wk[d];
  r[n] = expf(s);
}

// ---------------- K3: Z (sum H*r) and S2 (sum H*r^2) per column, per branch ----------------
__global__ __launch_bounds__(256) void k_colsum(const int* __restrict__ H, const float* __restrict__ r,
    float* __restrict__ Zu, float* __restrict__ Zi, float* __restrict__ S2u, float* __restrict__ S2i)
{
  int g = blockIdx.x*256 + threadIdx.x;
  int n0 = blockIdx.y*282;
  int n1 = n0+282; if (n1>NTOT) n1=NTOT;
  float zu=0.f, zi=0.f, su=0.f, si=0.f;
  for (int n=n0;n<n1;n++){
    float hv = (float)H[(size_t)n*G + g];
    float rv = r[n];
    float hr = hv*rv;
    if (n<NU){ zu += hr; su += hr*rv; } else { zi += hr; si += hr*rv; }
  }
  atomicAdd(&Zu[g], zu);
  atomicAdd(&Zi[g], zi);
  atomicAdd(&S2u[g], su);
  atomicAdd(&S2i[g], si);
}

// ---------------- K4: C = 1/Z, all-masked flags, ninv = 1/||w_row||  ----------------
__global__ void k_prepC(const float* Zu, const float* Zi, const float* S2u, const float* S2i,
                        float* Cu, float* Ci, int* Fu, int* Fi, float* ninv){
  int g = blockIdx.x*256+threadIdx.x;
  if (g>=G) return;
  float zu=Zu[g], zi=Zi[g];
  float cu = zu>0.f ? 1.f/zu : 0.f; int fu = !(zu>0.f);
  float ci = zi>0.f ? 1.f/zi : 0.f; int fi = !(zi>0.f);
  Cu[g]=cu; Fu[g]=fu; Ci[g]=ci; Fi[g]=fi;
  // norms^2 = sum_n w^2 ; H in {0,1} so H^2=H -> per branch: C^2 * sum(H r^2); uniform case: 1/N
  float nu = fu ? (1.f/(float)NU) : S2u[g]*cu*cu;
  float ni = fi ? (1.f/(float)NI) : S2i[g]*ci*ci;
  ninv[g] = rsqrtf(nu+ni);
}

// ---------------- K5: build wT (G x KP) AND Wtt (KP x G) from H ----------------
__global__ __launch_bounds__(256) void k_buildWT(const int* __restrict__ H, const float* __restrict__ r,
    const float* __restrict__ Cu, const float* __restrict__ Ci,
    const int* __restrict__ Fu, const int* __restrict__ Fi,
    unsigned short* __restrict__ wT, unsigned short* __restrict__ wtt)
{
  __shared__ float tile[64][65];
  int n0 = blockIdx.x*64, g0 = blockIdx.y*64;
  int tc = threadIdx.x&63, tr = threadIdx.x>>6;
  #pragma unroll
  for (int i=0;i<16;i++){
    int rr = tr + i*4; int n = n0+rr;
    float val = 0.f;
    if (n < NTOT) val = (float)H[(size_t)n*G + g0+tc] * r[n];
    tile[rr][tc] = val;
  }
  __syncthreads();
  int br = (n0 >= NU);
  const float* C = br ? Ci : Cu;
  const int*  F = br ? Fi : Fu;
  float invN = br ? (1.f/(float)NI) : (1.f/(float)NU);
  // wT[g][n]  (transposed access of tile)
  #pragma unroll
  for (int i=0;i<16;i++){
    int gg = tr + i*4; int g = g0+gg;
    int n = n0 + tc;
    float wv;
    if (n >= NTOT)   wv = 0.f;
    else if (F[g])   wv = invN;
    else             wv = tile[tc][gg] * C[g];
    wT[(size_t)g*KP + n] = f2b(wv);
  }
  // wtt[n][g]  (direct access of tile)
  float Cl = C[g0+tc]; int Fl = F[g0+tc];
  #pragma unroll
  for (int i=0;i<16;i++){
    int rr = tr + i*4; int n = n0 + rr;
    float wv;
    if (n >= NTOT)   wv = 0.f;
    else if (Fl)     wv = invN;
    else             wv = tile[rr][tc] * Cl;
    wtt[(size_t)n*G + g0+tc] = f2b(wv);
  }
}

// ---------------- K6: vt (128 x KP): branch-separated transposed V, zero-padded ----------------
__global__ __launch_bounds__(256) void k_buildVT(const unsigned short* __restrict__ vrow, unsigned short* __restrict__ vt){
  __shared__ unsigned short tile[64][65];
  int n0 = blockIdx.x*64;
  int tc = threadIdx.x&63, tr = threadIdx.x>>6;
  #pragma unroll
  for (int i=0;i<16;i++){
    int rr = tr+i*4; int n = n0+rr;
    tile[rr][tc] = (n<NTOT) ? vrow[(size_t)n*64+tc] : (unsigned short)0;
  }
  __syncthreads();
  int off = (n0>=NU) ? 64 : 0;
  int other = off ^ 64;
  #pragma unroll
  for (int i=0;i<16;i++){
    int dd = tr+i*4;
    vt[(size_t)(off  +dd)*KP + n0+tc] = tile[tc][dd];
    vt[(size_t)(other+dd)*KP + n0+tc] = 0;
  }
}

// ---------------- K7: bf16 GEMM  C(I,J) = A . B^T  (both k-contig rows), swizzled LDS ----------------
__global__ __launch_bounds__(256) void k_gemm_bt(
    const unsigned short* __restrict__ A, const unsigned short* __restrict__ B,
    float* __restrict__ Cf, unsigned short* __restrict__ Cb,
    const float* __restrict__ rowScale,
    long ldA, long ldB, long ldc, int ktn, int doAtomic)
{
  __shared__ __align__(16) unsigned short As[128*64];
  __shared__ __align__(16) unsigned short Bs[128*64];
  int t=threadIdx.x, wave=t>>6, lane=t&63;
  int I=blockIdx.x, J=blockIdx.y;
  int kt0 = blockIdx.z*ktn;
  f32x4 acc[4][4];
  #pragma unroll
  for (int mi=0;mi<4;mi++)
    #pragma unroll
    for (int ni=0;ni<4;ni++){
      acc[mi][ni][0]=0.f; acc[mi][ni][1]=0.f; acc[mi][ni][2]=0.f; acc[mi][ni][3]=0.f;
    }
  int l7 = lane&7, q4 = lane>>4, cl15 = lane&15;
  int rowOff = wave*8 + (lane>>3);
  int cchunk = (lane&7) ^ ((lane>>3)&7);       // swizzled global chunk for staging
  const unsigned short* Abase = A + (long)I*128*ldA + (long)cchunk*8;
  const unsigned short* Bbase = B + (long)J*128*ldB + (long)cchunk*8;
  unsigned short* AsW = As + wave*512;
  unsigned short* BsW = Bs + wave*512;
  int mrow0 = (wave&1)*64, nrow0 = (wave>>1)*64;
  for (int kt=kt0; kt<kt0+ktn; ++kt){
    long k0 = (long)kt*64;
    #pragma unroll
    for (int rr=0; rr<4; rr++){
      async16(AsW + rr*2048, Abase + (long)(rr*32 + rowOff)*ldA + k0);
      async16(BsW + rr*2048, Bbase + (long)(rr*32 + rowOff)*ldB + k0);
    }
    __syncthreads();
    #pragma unroll
    for (int kk=0; kk<2; kk++){
      int xoff = ((kk*4 + q4) ^ l7)*8;         // swizzled chunk on read
      bf16x8 af[4], bfv[4];
      #pragma unroll
      for (int mi=0;mi<4;mi++)
        af[mi] = *(const bf16x8*)(As + (mrow0 + mi*16 + cl15)*64 + xoff);
      #pragma unroll
      for (int ni=0;ni<4;ni++)
        bfv[ni] = *(const bf16x8*)(Bs + (nrow0 + ni*16 + cl15)*64 + xoff);
      #pragma unroll
      for (int mi=0;mi<4;mi++)
        #pragma unroll
        for (int ni=0;ni<4;ni++)
          acc[mi][ni] = __builtin_amdgcn_mfma_f32_16x16x32_bf16(af[mi], bfv[ni], acc[mi][ni], 0,0,0);
    }
    __syncthreads();
  }
  int cq = lane>>4, cl = lane&15;
  #pragma unroll
  for (int mi=0;mi<4;mi++)
    #pragma unroll
    for (int ni=0;ni<4;ni++)
      #pragma unroll
      for (int rg=0;rg<4;rg++){
        int gi = I*128 + mrow0 + mi*16 + cq*4 + rg;
        int hi = J*128 + nrow0 + ni*16 + cl;
        float v = acc[mi][ni][rg];
        if (rowScale) v *= rowScale[gi];
        if (doAtomic) atomicAdd(&Cf[(size_t)gi*ldc + hi], v);
        else          Cb[(size_t)gi*ldc + hi] = f2b(v);
      }
}

// ---------------- K9: gfsT[d][g] = bf16(gf[g][d] * ninv[g]) ----------------
__global__ __launch_bounds__(256) void k_buildGfsT(const float* __restrict__ gf, const float* __restrict__ ninv,
                                                   unsigned short* __restrict__ gfsT){
  __shared__ float tile[64][65];
  int g0 = blockIdx.x*64, d0 = blockIdx.y*64;
  int tc=threadIdx.x&63, tr=threadIdx.x>>6;
  #pragma unroll
  for (int i=0;i<16;i++){
    int rr=tr+i*4;
    tile[rr][tc] = gf[(size_t)(g0+rr)*128 + d0+tc] * ninv[g0+rr];
  }
  __syncthreads();
  #pragma unroll
  for (int i=0;i<16;i++){
    int dd=tr+i*4;
    gfsT[(size_t)(d0+dd)*G + g0+tc] = f2b(tile[tc][dd]);
  }
}

// ---------------- K10: u[k] = sum_g wT[g][k] * ninv[g]  (column pass) ----------------
__global__ __launch_bounds__(256) void k_u(const unsigned short* __restrict__ wT,
                                           const float* __restrict__ ninv, float* __restrict__ u){
  int k = blockIdx.x*256 + threadIdx.x;
  if (k >= KP) return;
  int g0 = blockIdx.y*512;
  float s = 0.f;
  for (int j=0;j<512;j++){
    float nv = ninv[g0+j];
    s += bfu(wT[(size_t)(g0+j)*KP + k]) * nv;
  }
  atomicAdd(&u[k], s);
}

// ---------------- K11: deg[h] = ninv[h] * dot(wT[h,:], u) ----------------
__global__ __launch_bounds__(256) void k_degv(const unsigned short* __restrict__ wT,
                                              const float* __restrict__ u, const float* __restrict__ ninv,
                                              float* __restrict__ deg){
  int t=threadIdx.x, wave=t>>6, lane=t&63;
  int h = blockIdx.x*4 + wave;
  const unsigned short* row = wT + (size_t)h*KP;
  float s=0.f;
  for (int k=lane;k<KP;k+=64) s += bfu(row[k])*u[k];
  #pragma unroll
  for (int off=32; off>0; off>>=1) s += __shfl_down(s, off, 64);
  if (lane==0) deg[h] = ninv[h]*s;
}

// ---------------- K12: agg = 0.8 gf + 0.2 msg/deg ; out = sigmoid(agg @ gW^T + gb) ----------------
__global__ __launch_bounds__(256) void k_final(const float* __restrict__ gf, const float* __restrict__ msg,
    const float* __restrict__ deg, const float* __restrict__ gW, const float* __restrict__ gb,
    float* __restrict__ out)
{
  __shared__ float Wl[64*129];
  __shared__ float aggL[4][128];
  __shared__ float gbL[64];
  int t=threadIdx.x;
  for (int e=t; e<8192; e+=256){ int o=e>>7, dd=e&127; Wl[o*129+dd] = gW[e]; }
  if (t<64) gbL[t] = gb[t];
  int g0 = blockIdx.x*4;
  for (int e=t; e<512; e+=256){
    int gl=e>>7, dd=e&127; int g=g0+gl;
    float dv = deg[g];
    float hn = dv>0.f ? msg[(size_t)g*128+dd]/dv : 0.f;
    aggL[gl][dd] = 0.8f*gf[(size_t)g*128+dd] + 0.2f*hn;
  }
  __syncthreads();
  int gl = t>>6, o = t&63;
  float s = gbL[o];
  #pragma unroll
  for (int dd=0; dd<128; dd++) s += aggL[gl][dd]*Wl[o*129+dd];
  out[(size_t)(g0+gl)*64 + o] = 1.f/(1.f+expf(-s));
}

extern "C" void kernel_launch(void* const* d_in, const int* in_sizes, int n_in,
                              void* d_out, int out_size, void* d_ws, size_t ws_size,
                              hipStream_t stream)
{
  (void)in_sizes; (void)n_in; (void)out_size; (void)ws_size;
  const int* H = (const int*)d_in[0];
  const float* feats = (const float*)d_in[1];
  const float* uWq=(const float*)d_in[3];
  const float* ubq=(const float*)d_in[4];
  const float* uWk=(const float*)d_in[5];
  const float* ubk=(const float*)d_in[6];
  const float* uWv=(const float*)d_in[7];
  const float* ubv=(const float*)d_in[8];
  const float* uWs=(const float*)d_in[9];
  const float* ubs=(const float*)d_in[10];
  const float* iWq=(const float*)d_in[11];
  const float* ibq=(const float*)d_in[12];
  const float* iWk=(const float*)d_in[13];
  const float* ibk=(const float*)d_in[14];
  const float* iWv=(const float*)d_in[15];
  const float* ibv=(const float*)d_in[16];
  const float* iWs=(const float*)d_in[17];
  const float* ibs=(const float*)d_in[18];
  const float* gW =(const float*)d_in[19];
  const float* gb =(const float*)d_in[20];
  float* out = (float*)d_out;

  char* p = (char*)d_ws;
  auto alloc=[&](size_t b)->void*{ void* r=(void*)p; p += (b+255)&~(size_t)255; return r; };
  unsigned short* wT  = (unsigned short*)alloc((size_t)G*KP*2);
  unsigned short* wtt = (unsigned short*)alloc((size_t)KP*G*2);
  unsigned short* vt  = (unsigned short*)alloc((size_t)128*KP*2);
  unsigned short* tmpTb=(unsigned short*)alloc((size_t)128*KP*2);
  float* q    = (float*)alloc((size_t)NTOT*64*4);
  unsigned short* vrow=(unsigned short*)alloc((size_t)NTOT*64*2);
  float* r    = (float*)alloc((size_t)NTOT*4);
  float* Zu   = (float*)alloc(G*4);
  float* Zi   = (float*)alloc(G*4);
  float* S2u  = (float*)alloc(G*4);
  float* S2i  = (float*)alloc(G*4);
  float* Cu   = (float*)alloc(G*4);
  float* Ci   = (float*)alloc(G*4);
  int*   Fu   = (int*)alloc(G*4);
  int*   Fi   = (int*)alloc(G*4);
  float* wsk  = (float*)alloc(128*4);
  float* gf   = (float*)alloc((size_t)G*128*4);
  unsigned short* gfsT = (unsigned short*)alloc((size_t)128*G*2);
  float* ninv = (float*)alloc(G*4);
  float* msg  = (float*)alloc((size_t)G*128*4);
  float* u    = (float*)alloc((size_t)KP*4);
  float* deg  = (float*)alloc(G*4);

  hipMemsetAsync(wsk, 0, 128*4, stream);
  hipMemsetAsync(Zu,  0, G*4, stream);
  hipMemsetAsync(Zi,  0, G*4, stream);
  hipMemsetAsync(S2u, 0, G*4, stream);
  hipMemsetAsync(S2i, 0, G*4, stream);
  hipMemsetAsync(gf,  0, (size_t)G*128*4, stream);
  hipMemsetAsync(msg, 0, (size_t)G*128*4, stream);
  hipMemsetAsync(u,   0, (size_t)KP*4, stream);

  k_proj<<<128,256,0,stream>>>(feats, uWq,ubq,uWk,ubk,uWv,ubv,uWs,
                               iWq,ibq,iWk,ibk,iWv,ibv,iWs, q, vrow, wsk);
  k_score<<<(NTOT+255)/256,256,0,stream>>>(q, wsk, ubs, ibs, r);
  k_colsum<<<dim3(16,64),256,0,stream>>>(H, r, Zu, Zi, S2u, S2i);
  k_prepC<<<16,256,0,stream>>>(Zu,Zi,S2u,S2i,Cu,Ci,Fu,Fi,ninv);
  k_buildWT<<<dim3(KT,64),256,0,stream>>>(H, r, Cu, Ci, Fu, Fi, wT, wtt);
  k_buildVT<<<KT,256,0,stream>>>(vrow, vt);
  // group_feats = wT . vt^T   (split-K, atomic f32)
  k_gemm_bt<<<dim3(32,1,6),256,0,stream>>>(wT, vt, gf, nullptr, nullptr,
                                           (long)KP, (long)KP, 128, 47, 1);
  // gfsT = (D . gf)^T  (bf16, g-contiguous rows)
  k_buildGfsT<<<dim3(64,2),256,0,stream>>>(gf, ninv, gfsT);
  // tmpT(128 x KP) = gfsT . wtt^T  ->  tmpT[d][n] = sum_g (D gf)[g][d] * W[g][n]
  k_gemm_bt<<<dim3(1,141,1),256,0,stream>>>(gfsT, wtt, nullptr, tmpTb, nullptr,
                                            (long)G, (long)G, (long)KP, 64, 0);
  // msg = D . (wT . tmpT^T)   (split-K, atomic, row-scaled by ninv)
  k_gemm_bt<<<dim3(32,1,6),256,0,stream>>>(wT, tmpTb, msg, nullptr, ninv,
                                           (long)KP, (long)KP, 128, 47, 1);
  // u = W^T ninv ; deg = D . (W u)
  k_u<<<dim3((KP+255)/256,8),256,0,stream>>>(wT, ninv, u);
  k_degv<<<G/4,256,0,stream>>>(wT, u, ninv, deg);
  k_final<<<G/4,256,0,stream>>>(gf, msg, deg, gW, gb, out);
}

// Round 5
// 958.771 us; speedup vs baseline: 1.8627x; 1.3455x over previous
//
#include <hip/hip_runtime.h>
#include <hip/hip_bf16.h>
#include <cstdint>
#include <cstddef>

#define NU   8000
#define NI   10000
#define NTOT 18000
#define G    4096
#define KP2  18176      // users 0..8063 (126 tiles of 64), items 8064..18175 (158 tiles)
#define KT2  284
#define UT   126        // user k-tiles (64-wide)
#define IT   158        // item k-tiles

typedef __attribute__((ext_vector_type(8))) short bf16x8;
typedef __attribute__((ext_vector_type(4))) float f32x4;

__device__ __forceinline__ float bfu(unsigned short u){
  return __uint_as_float(((unsigned)u)<<16);
}
__device__ __forceinline__ unsigned short f2b(float f){
  __hip_bfloat16 h = __float2bfloat16(f);
  return __builtin_bit_cast(unsigned short, h);
}
__device__ __forceinline__ void async16(void* lds, const void* g){
  __builtin_amdgcn_global_load_lds((const __attribute__((address_space(1))) unsigned int*)g,
                                   (__attribute__((address_space(3))) unsigned int*)lds, 16, 0, 0);
}
// slot -> source row n, or -1 for pad
__device__ __forceinline__ int slot2n(int s){
  return (s < 8064) ? (s < 8000 ? s : -1) : (s-64 < NTOT ? s-64 : -1);
}

// ---------------- K1: q/k/v projections, v rows, wsk = Ws @ k ----------------
__global__ __launch_bounds__(256) void k_proj(
    const float* __restrict__ feats,
    const float* uWq, const float* ubq, const float* uWk, const float* ubk,
    const float* uWv, const float* ubv, const float* uWs,
    const float* iWq, const float* ibq, const float* iWk, const float* ibk,
    const float* iWv, const float* ibv, const float* iWs,
    float* __restrict__ q, unsigned short* __restrict__ vrow, float* __restrict__ wsk)
{
  __shared__ unsigned short Wt[6*4096];
  __shared__ float bl[6*64];
  __shared__ float wacc[128];
  const float* mats[6]  = {uWq,uWk,uWv,iWq,iWk,iWv};
  const float* bias6[6] = {ubq,ubk,ubv,ibq,ibk,ibv};
  int t = threadIdx.x;
  for (int m=0;m<6;m++)
    for (int e=t; e<4096; e+=256){
      int dd = e>>6, jj = e&63;
      Wt[m*4096 + jj*64 + dd] = f2b(mats[m][e]);
    }
  for (int e=t; e<384; e+=256) bl[e] = bias6[e>>6][e&63];
  if (t<128) wacc[t]=0.f;
  __syncthreads();
  int wave=t>>6, lane=t&63;
  int gw = blockIdx.x*4+wave, nw = gridDim.x*4;
  float accU=0.f, accI=0.f;
  for (int n=gw; n<NTOT; n+=nw){
    int br = (n>=NU);
    const unsigned short* W = Wt + br*3*4096;
    const float* bb = bl + br*192;
    float x = feats[(size_t)n*64+lane];
    float qd=bb[lane], kd=bb[64+lane], vd=bb[128+lane];
    #pragma unroll 16
    for (int j=0;j<64;j++){
      float xj = __shfl(x, j, 64);
      qd += xj * bfu(W[       j*64+lane]);
      kd += xj * bfu(W[4096 + j*64+lane]);
      vd += xj * bfu(W[8192 + j*64+lane]);
    }
    q[(size_t)n*64+lane] = qd;
    vrow[(size_t)n*64+lane] = f2b(vd);
    float wsn = br ? iWs[n-NU] : uWs[n];
    if (br) accI += wsn*kd; else accU += wsn*kd;
  }
  atomicAdd(&wacc[lane], accU);
  atomicAdd(&wacc[64+lane], accI);
  __syncthreads();
  if (t<128) atomicAdd(&wsk[t], wacc[t]);
}

// ---------------- K2: r[n] = exp(q . wsk + bs) ----------------
__global__ __launch_bounds__(256) void k_score(const float* __restrict__ q, const float* __restrict__ wsk,
    const float* ubs, const float* ibs, float* __restrict__ r)
{
  __shared__ float wl[128];
  int t=threadIdx.x;
  if (t<128) wl[t]=wsk[t];
  __syncthreads();
  int n = blockIdx.x*256+t;
  if (n>=NTOT) return;
  int br = (n>=NU);
  const float* wk = wl + br*64;
  float s = br ? ibs[0] : ubs[0];
  const float* qr = q + (size_t)n*64;
  #pragma unroll
  for (int d=0;d<64;d++) s += qr[d]*wk[d];
  r[n] = expf(s);
}

// ---------------- K3: fused build of W' (both layouts) + colsums (ONE pass over H) ----------------
// wT[g][slot] = H[n,g]*r[n] (bf16), wtt[slot][g] same; Z = sum_n H*r, S2 = sum_n H*r^2 per branch.
__global__ __launch_bounds__(256) void k_buildW(
    const int* __restrict__ H, const float* __restrict__ r,
    unsigned short* __restrict__ wT, unsigned short* __restrict__ wtt,
    float* __restrict__ Zu, float* __restrict__ Zi,
    float* __restrict__ S2u, float* __restrict__ S2i)
{
  __shared__ float T[64][65];
  __shared__ float rl[64];
  __shared__ float zp[4][64];
  __shared__ float sp[4][64];
  int t = threadIdx.x;
  int s0 = blockIdx.x*64;
  int g0 = blockIdx.y*64;
  int isItem = (s0 >= 8064);
  if (t < 64){
    int n = slot2n(s0 + t);
    rl[t] = (n >= 0) ? r[n] : 0.f;
  }
  __syncthreads();
  int rowb = t >> 4;            // 0..15
  int gq = (t & 15) * 4;        // g-chunk of 4
  #pragma unroll
  for (int i=0;i<4;i++){
    int row = rowb + 16*i;
    int s = s0 + row;
    int n = slot2n(s);
    float rv = rl[row];
    float v0=0.f,v1=0.f,v2=0.f,v3=0.f;
    if (n >= 0){
      int4 hv = *(const int4*)(H + (size_t)n*G + g0 + gq);
      v0 = hv.x*rv; v1 = hv.y*rv; v2 = hv.z*rv; v3 = hv.w*rv;
    }
    T[row][gq]=v0; T[row][gq+1]=v1; T[row][gq+2]=v2; T[row][gq+3]=v3;
    ushort4 pk; pk.x=f2b(v0); pk.y=f2b(v1); pk.z=f2b(v2); pk.w=f2b(v3);
    *(ushort4*)(wtt + (size_t)s*G + g0 + gq) = pk;
  }
  __syncthreads();
  // wT transposed write: 4 lanes per g-row, 16 slots (32B) each
  {
    int gl = t >> 2;
    int sc = (t & 3) * 16;
    __align__(16) unsigned short buf[16];
    #pragma unroll
    for (int j=0;j<16;j++) buf[j] = f2b(T[sc+j][gl]);
    *(uint4*)(wT + (size_t)(g0+gl)*KP2 + s0 + sc)     = *(uint4*)(buf);
    *(uint4*)(wT + (size_t)(g0+gl)*KP2 + s0 + sc + 8) = *(uint4*)(buf+8);
  }
  // column sums
  {
    int gl = t & 63, qq = t >> 6;
    float z=0.f, s2=0.f;
    #pragma unroll
    for (int j=0;j<16;j++){
      float v = T[qq*16+j][gl];
      z += v; s2 += v * rl[qq*16+j];
    }
    zp[qq][gl] = z; sp[qq][gl] = s2;
  }
  __syncthreads();
  if (t < 64){
    float z  = zp[0][t]+zp[1][t]+zp[2][t]+zp[3][t];
    float s2 = sp[0][t]+sp[1][t]+sp[2][t]+sp[3][t];
    if (isItem){ atomicAdd(&Zi[g0+t], z); atomicAdd(&S2i[g0+t], s2); }
    else       { atomicAdd(&Zu[g0+t], z); atomicAdd(&S2u[g0+t], s2); }
  }
}

// ---------------- K4: scales: C=1/Z, ninv=1/||w||, cn=C*ninv, flags ----------------
__global__ void k_prepC(const float* Zu, const float* Zi, const float* S2u, const float* S2i,
                        float* Cu, float* Ci, float* cnu, float* cni, float* ninv,
                        int* Fu, int* Fi){
  int g = blockIdx.x*256+threadIdx.x;
  if (g>=G) return;
  float zu=Zu[g], zi=Zi[g];
  int fu = !(zu>0.f), fi = !(zi>0.f);
  float cu = fu ? 1.f : 1.f/zu;
  float ci = fi ? 1.f : 1.f/zi;
  float nu  = fu ? (1.f/(float)NU) : S2u[g]*cu*cu;
  float ni_ = fi ? (1.f/(float)NI) : S2i[g]*ci*ci;
  float nv = rsqrtf(nu+ni_);
  Cu[g]=cu; Ci[g]=ci; ninv[g]=nv; cnu[g]=cu*nv; cni[g]=ci*nv;
  Fu[g]=fu; Fi[g]=fi;
}

// ---------------- K4b: patch all-masked columns (never runs in practice) ----------------
__global__ __launch_bounds__(256) void k_patchF(const int* __restrict__ Fu, const int* __restrict__ Fi,
    unsigned short* __restrict__ wT, unsigned short* __restrict__ wtt){
  int g = blockIdx.x, br = blockIdx.y;
  int flag = br ? Fi[g] : Fu[g];
  if (!flag) return;
  int s0 = br ? 8064 : 0;
  int cnt = br ? NI : NU;
  unsigned short v = f2b(1.f/(float)cnt);
  for (int k = threadIdx.x; k < cnt; k += 256){
    wT[(size_t)g*KP2 + s0 + k] = v;
    wtt[(size_t)(s0+k)*G + g] = v;
  }
}

// ---------------- K5: vt (128 x KP2), branch half selected by slot range ----------------
__global__ __launch_bounds__(256) void k_buildVT(const unsigned short* __restrict__ vrow,
                                                 unsigned short* __restrict__ vt){
  __shared__ unsigned short tile[64][65];
  int s0 = blockIdx.x*64;
  int tc = threadIdx.x&63, tr = threadIdx.x>>6;
  #pragma unroll
  for (int i=0;i<16;i++){
    int row = tr+i*4;
    int n = slot2n(s0+row);
    tile[row][tc] = (n>=0) ? vrow[(size_t)n*64+tc] : (unsigned short)0;
  }
  __syncthreads();
  int dOff = (s0 >= 8064) ? 64 : 0;
  #pragma unroll
  for (int i=0;i<16;i++){
    int dd = tr+i*4;
    vt[(size_t)(dOff+dd)*KP2 + s0+tc] = tile[tc][dd];
  }
}

// ---------------- K6: templated bf16 GEMM C = A.B^T (k-contig rows), swizzled LDS ----------------
// MODE 0: gf   = W'.vt^T, atomic f32, epilogue scale Cu/Ci by column half, grid (32,1,8)
// MODE 1: tmpT = gfsT2 . wtt^T, bf16 out, A-half selected by J (>=63 -> item half), grid (1,142,1)
// MODE 2: msg  = W'.tmpT^T, atomic f32, branch-pure z blocks scaled by cn; deg fused via u-column
template<int MODE>
__global__ __launch_bounds__(256) void k_gemm(
    const unsigned short* __restrict__ A, const unsigned short* __restrict__ B,
    float* __restrict__ Cf, unsigned short* __restrict__ Cb,
    const float* __restrict__ sU, const float* __restrict__ sI,
    const float* __restrict__ u, float* __restrict__ deg,
    long ldA, long ldB, long ldc)
{
  __shared__ __align__(16) unsigned short As[128*64];
  __shared__ __align__(16) unsigned short Bs[128*64];
  int t=threadIdx.x, wave=t>>6, lane=t&63;
  int I=blockIdx.x, J=blockIdx.y, z=blockIdx.z;
  int kt0=0, ktn=0;
  const float* scale = nullptr;
  if (MODE==0){ kt0 = z*36; ktn = min(36, KT2-kt0); }
  else if (MODE==1){ kt0 = 0; ktn = 64; }
  else {
    if (z<4){ kt0 = z*32;        ktn = min(32, UT-kt0);        scale = sU; }
    else    { kt0 = UT + (z-4)*40; ktn = min(40, KT2-kt0);     scale = sI; }
  }
  f32x4 acc[4][4];
  #pragma unroll
  for (int mi=0;mi<4;mi++)
    #pragma unroll
    for (int ni=0;ni<4;ni++){
      acc[mi][ni][0]=0.f; acc[mi][ni][1]=0.f; acc[mi][ni][2]=0.f; acc[mi][ni][3]=0.f;
    }
  f32x4 accd[4];
  if (MODE==2){
    #pragma unroll
    for (int mi=0;mi<4;mi++){ accd[mi][0]=0.f; accd[mi][1]=0.f; accd[mi][2]=0.f; accd[mi][3]=0.f; }
  }
  int l7 = lane&7, q4 = lane>>4, cl15 = lane&15;
  int rowOff = wave*8 + (lane>>3);
  int cchunk = (lane&7) ^ ((lane>>3)&7);
  long aRow0 = (MODE==1) ? ((J>=63)?128:0) : (long)I*128;
  const unsigned short* Abase = A + aRow0*ldA + (long)cchunk*8;
  const unsigned short* Bbase = B + (long)J*128*ldB + (long)cchunk*8;
  unsigned short* AsW = As + wave*512;
  unsigned short* BsW = Bs + wave*512;
  int mrow0 = (wave&1)*64, nrow0 = (wave>>1)*64;
  for (int kt=kt0; kt<kt0+ktn; ++kt){
    long k0 = (long)kt*64;
    #pragma unroll
    for (int rr=0; rr<4; rr++){
      async16(AsW + rr*2048, Abase + (long)(rr*32 + rowOff)*ldA + k0);
      async16(BsW + rr*2048, Bbase + (long)(rr*32 + rowOff)*ldB + k0);
    }
    __syncthreads();
    #pragma unroll
    for (int kk=0; kk<2; kk++){
      int xoff = ((kk*4 + q4) ^ l7)*8;
      bf16x8 af[4], bfv[4];
      #pragma unroll
      for (int mi=0;mi<4;mi++)
        af[mi] = *(const bf16x8*)(As + (mrow0 + mi*16 + cl15)*64 + xoff);
      #pragma unroll
      for (int ni=0;ni<4;ni++)
        bfv[ni] = *(const bf16x8*)(Bs + (nrow0 + ni*16 + cl15)*64 + xoff);
      #pragma unroll
      for (int mi=0;mi<4;mi++)
        #pragma unroll
        for (int ni=0;ni<4;ni++)
          acc[mi][ni] = __builtin_amdgcn_mfma_f32_16x16x32_bf16(af[mi], bfv[ni], acc[mi][ni], 0,0,0);
      if (MODE==2){
        bf16x8 bu = {0,0,0,0,0,0,0,0};
        if (cl15==0){
          const float* up = u + kt*64 + kk*32 + q4*8;
          float4 ua = *(const float4*)up;
          float4 ub = *(const float4*)(up+4);
          union { bf16x8 v; unsigned short s[8]; } uu;
          uu.s[0]=f2b(ua.x); uu.s[1]=f2b(ua.y); uu.s[2]=f2b(ua.z); uu.s[3]=f2b(ua.w);
          uu.s[4]=f2b(ub.x); uu.s[5]=f2b(ub.y); uu.s[6]=f2b(ub.z); uu.s[7]=f2b(ub.w);
          bu = uu.v;
        }
        #pragma unroll
        for (int mi=0;mi<4;mi++)
          accd[mi] = __builtin_amdgcn_mfma_f32_16x16x32_bf16(af[mi], bu, accd[mi], 0,0,0);
      }
    }
    __syncthreads();
  }
  int cq = lane>>4, cl = lane&15;
  #pragma unroll
  for (int mi=0;mi<4;mi++)
    #pragma unroll
    for (int ni=0;ni<4;ni++)
      #pragma unroll
      for (int rg=0;rg<4;rg++){
        int gi = (MODE==1 ? 0 : I*128) + mrow0 + mi*16 + cq*4 + rg;
        int hi = J*128 + nrow0 + ni*16 + cl;
        float v = acc[mi][ni][rg];
        if (MODE==0){
          float sc = (hi & 64) ? sI[gi] : sU[gi];
          atomicAdd(&Cf[(size_t)gi*ldc + hi], v*sc);
        } else if (MODE==1){
          Cb[(size_t)gi*ldc + hi] = f2b(v);
        } else {
          atomicAdd(&Cf[(size_t)gi*ldc + hi], v*scale[gi]);
        }
      }
  if (MODE==2 && cl15==0){
    #pragma unroll
    for (int mi=0;mi<4;mi++)
      #pragma unroll
      for (int rg=0;rg<4;rg++){
        int gi = I*128 + mrow0 + mi*16 + cq*4 + rg;
        atomicAdd(&deg[gi], accd[mi][rg]*scale[gi]);
      }
  }
}

// ---------------- K7: gfsT2 (256 x G): rows d = gf*ninv*Cu, rows 128+d = gf*ninv*Ci ----------------
__global__ __launch_bounds__(256) void k_buildGfsT2(const float* __restrict__ gf, const float* __restrict__ ninv,
    const float* __restrict__ Cu, const float* __restrict__ Ci, unsigned short* __restrict__ gfsT2){
  __shared__ float tile[64][65];
  int g0 = blockIdx.x*64, d0 = blockIdx.y*64;
  int tc=threadIdx.x&63, tr=threadIdx.x>>6;
  #pragma unroll
  for (int i=0;i<16;i++){
    int rr=tr+i*4;
    tile[rr][tc] = gf[(size_t)(g0+rr)*128 + d0+tc] * ninv[g0+rr];
  }
  __syncthreads();
  #pragma unroll
  for (int i=0;i<16;i++){
    int dd=tr+i*4;
    float v = tile[tc][dd];
    int g = g0+tc;
    gfsT2[(size_t)(d0+dd)*G + g]       = f2b(v*Cu[g]);
    gfsT2[(size_t)(128+d0+dd)*G + g]   = f2b(v*Ci[g]);
  }
}

// ---------------- K8: u[k] = sum_g W'[g,k]*cn_b(k)[g], vectorized ----------------
__global__ __launch_bounds__(256) void k_u(const unsigned short* __restrict__ wT,
    const float* __restrict__ cnu, const float* __restrict__ cni, float* __restrict__ u){
  long k0 = ((long)blockIdx.x*256 + threadIdx.x)*8;
  if (k0 >= KP2) return;
  int g0 = blockIdx.y*512;
  const float* cn = (k0 < 8064) ? cnu : cni;
  float a[8];
  #pragma unroll
  for (int j=0;j<8;j++) a[j]=0.f;
  for (int j=0;j<512;j++){
    float c = cn[g0+j];
    bf16x8 w = *(const bf16x8*)(wT + (size_t)(g0+j)*KP2 + k0);
    #pragma unroll
    for (int e=0;e<8;e++) a[e] += bfu((unsigned short)w[e])*c;
  }
  #pragma unroll
  for (int e=0;e<8;e++) atomicAdd(&u[k0+e], a[e]);
}

// ---------------- K9: agg = 0.8 gf + 0.2 msg/deg ; out = sigmoid(agg @ gW^T + gb) ----------------
__global__ __launch_bounds__(256) void k_final(const float* __restrict__ gf, const float* __restrict__ msg,
    const float* __restrict__ deg, const float* __restrict__ gW, const float* __restrict__ gb,
    float* __restrict__ out)
{
  __shared__ float Wl[64*129];
  __shared__ float aggL[4][128];
  __shared__ float gbL[64];
  int t=threadIdx.x;
  for (int e=t; e<8192; e+=256){ int o=e>>7, dd=e&127; Wl[o*129+dd] = gW[e]; }
  if (t<64) gbL[t] = gb[t];
  int g0 = blockIdx.x*4;
  for (int e=t; e<512; e+=256){
    int gl=e>>7, dd=e&127; int g=g0+gl;
    float dv = deg[g];
    float hn = dv>0.f ? msg[(size_t)g*128+dd]/dv : 0.f;
    aggL[gl][dd] = 0.8f*gf[(size_t)g*128+dd] + 0.2f*hn;
  }
  __syncthreads();
  int gl = t>>6, o = t&63;
  float s = gbL[o];
  #pragma unroll
  for (int dd=0; dd<128; dd++) s += aggL[gl][dd]*Wl[o*129+dd];
  out[(size_t)(g0+gl)*64 + o] = 1.f/(1.f+expf(-s));
}

extern "C" void kernel_launch(void* const* d_in, const int* in_sizes, int n_in,
                              void* d_out, int out_size, void* d_ws, size_t ws_size,
                              hipStream_t stream)
{
  (void)in_sizes; (void)n_in; (void)out_size; (void)ws_size;
  const int* H = (const int*)d_in[0];
  const float* feats = (const float*)d_in[1];
  const float* uWq=(const float*)d_in[3];
  const float* ubq=(const float*)d_in[4];
  const float* uWk=(const float*)d_in[5];
  const float* ubk=(const float*)d_in[6];
  const float* uWv=(const float*)d_in[7];
  const float* ubv=(const float*)d_in[8];
  const float* uWs=(const float*)d_in[9];
  const float* ubs=(const float*)d_in[10];
  const float* iWq=(const float*)d_in[11];
  const float* ibq=(const float*)d_in[12];
  const float* iWk=(const float*)d_in[13];
  const float* ibk=(const float*)d_in[14];
  const float* iWv=(const float*)d_in[15];
  const float* ibv=(const float*)d_in[16];
  const float* iWs=(const float*)d_in[17];
  const float* ibs=(const float*)d_in[18];
  const float* gW =(const float*)d_in[19];
  const float* gb =(const float*)d_in[20];
  float* out = (float*)d_out;

  char* p = (char*)d_ws;
  auto alloc=[&](size_t b)->void*{ void* r=(void*)p; p += (b+255)&~(size_t)255; return r; };
  unsigned short* wT   = (unsigned short*)alloc((size_t)G*KP2*2);
  unsigned short* wtt  = (unsigned short*)alloc((size_t)KP2*G*2);
  unsigned short* vt   = (unsigned short*)alloc((size_t)128*KP2*2);
  unsigned short* tmpTb= (unsigned short*)alloc((size_t)128*KP2*2);
  unsigned short* gfsT2= (unsigned short*)alloc((size_t)256*G*2);
  float* q    = (float*)alloc((size_t)NTOT*64*4);
  unsigned short* vrow=(unsigned short*)alloc((size_t)NTOT*64*2);
  float* r    = (float*)alloc((size_t)NTOT*4);
  float* Zu   = (float*)alloc(G*4);
  float* Zi   = (float*)alloc(G*4);
  float* S2u  = (float*)alloc(G*4);
  float* S2i  = (float*)alloc(G*4);
  float* Cu   = (float*)alloc(G*4);
  float* Ci   = (float*)alloc(G*4);
  float* cnu  = (float*)alloc(G*4);
  float* cni  = (float*)alloc(G*4);
  float* ninv = (float*)alloc(G*4);
  int*   Fu   = (int*)alloc(G*4);
  int*   Fi   = (int*)alloc(G*4);
  float* wsk  = (float*)alloc(128*4);
  float* gf   = (float*)alloc((size_t)G*128*4);
  float* msg  = (float*)alloc((size_t)G*128*4);
  float* u    = (float*)alloc((size_t)KP2*4);
  float* deg  = (float*)alloc(G*4);

  hipMemsetAsync(wsk, 0, 128*4, stream);
  hipMemsetAsync(Zu,  0, G*4, stream);
  hipMemsetAsync(Zi,  0, G*4, stream);
  hipMemsetAsync(S2u, 0, G*4, stream);
  hipMemsetAsync(S2i, 0, G*4, stream);
  hipMemsetAsync(gf,  0, (size_t)G*128*4, stream);
  hipMemsetAsync(msg, 0, (size_t)G*128*4, stream);
  hipMemsetAsync(u,   0, (size_t)KP2*4, stream);
  hipMemsetAsync(deg, 0, G*4, stream);
  hipMemsetAsync(vt,  0, (size_t)128*KP2*2, stream);

  k_proj<<<128,256,0,stream>>>(feats, uWq,ubq,uWk,ubk,uWv,ubv,uWs,
                               iWq,ibq,iWk,ibk,iWv,ibv,iWs, q, vrow, wsk);
  k_score<<<(NTOT+255)/256,256,0,stream>>>(q, wsk, ubs, ibs, r);
  // ONE pass over H: W' in both layouts + Z + S2
  k_buildW<<<dim3(KT2,64),256,0,stream>>>(H, r, wT, wtt, Zu, Zi, S2u, S2i);
  k_prepC<<<16,256,0,stream>>>(Zu,Zi,S2u,S2i,Cu,Ci,cnu,cni,ninv,Fu,Fi);
  k_patchF<<<dim3(G,2),256,0,stream>>>(Fu,Fi,wT,wtt);
  k_buildVT<<<KT2,256,0,stream>>>(vrow, vt);
  // gf = (Cu|Ci per half) * (W' . vt^T)
  k_gemm<0><<<dim3(32,1,8),256,0,stream>>>(wT, vt, gf, nullptr, Cu, Ci, nullptr, nullptr,
                                           (long)KP2, (long)KP2, 128);
  k_buildGfsT2<<<dim3(64,2),256,0,stream>>>(gf, ninv, Cu, Ci, gfsT2);
  // tmpT[d][n] = sum_g (D gf C_b(n))[g,d] * W'[g,n]
  k_gemm<1><<<dim3(1,142,1),256,0,stream>>>(gfsT2, wtt, nullptr, tmpTb, nullptr, nullptr, nullptr, nullptr,
                                            (long)G, (long)G, (long)KP2);
  // u = W'^T cn (branch-selected)
  k_u<<<dim3(9,8),256,0,stream>>>(wT, cnu, cni, u);
  // msg = sum_b cn_b * (W'_b . tmpT^T)  with deg fused as extra u-column
  k_gemm<2><<<dim3(32,1,8),256,0,stream>>>(wT, tmpTb, msg, nullptr, cnu, cni, u, deg,
                                           (long)KP2, (long)KP2, 128);
  k_final<<<G/4,256,0,stream>>>(gf, msg, deg, gW, gb, out);
}

// Round 7
// 830.110 us; speedup vs baseline: 2.1514x; 1.1550x over previous
//
#include <hip/hip_runtime.h>
#include <hip/hip_bf16.h>
#include <cstdint>
#include <cstddef>

#define NU   8000
#define NI   10000
#define NTOT 18000
#define G    4096
#define KP2  18176      // slots: users 0..8063, items 8064..18175
#define NSL  284        // 64-slot tiles
#define KT8  142        // 128-byte k-tiles
#define UT8  63         // user 128-tiles (63*128 = 8064)

typedef __attribute__((ext_vector_type(4))) float f32x4;

__device__ __forceinline__ float bfu(unsigned short u){
  return __uint_as_float(((unsigned)u)<<16);
}
__device__ __forceinline__ unsigned short f2b(float f){
  __hip_bfloat16 h = __float2bfloat16(f);
  return __builtin_bit_cast(unsigned short, h);
}
__device__ __forceinline__ unsigned char f2f8(float v){
  int p = __builtin_amdgcn_cvt_pk_fp8_f32(v, 0.f, 0, false);
  return (unsigned char)(p & 0xff);
}
template<int SEL>
__device__ __forceinline__ float f8tof(unsigned int w){
  return __builtin_amdgcn_cvt_f32_fp8((int)w, SEL);
}
__device__ __forceinline__ void async16(void* lds, const void* g){
  __builtin_amdgcn_global_load_lds((const __attribute__((address_space(1))) unsigned int*)g,
                                   (__attribute__((address_space(3))) unsigned int*)lds, 16, 0, 0);
}
__device__ __forceinline__ int slot2n(int s){
  return (s < 8064) ? (s < 8000 ? s : -1) : (s-64 < NTOT ? s-64 : -1);
}

// ---------------- K1: q/k/v projections, v rows, wsk = Ws @ k ----------------
__global__ __launch_bounds__(256) void k_proj(
    const float* __restrict__ feats,
    const float* uWq, const float* ubq, const float* uWk, const float* ubk,
    const float* uWv, const float* ubv, const float* uWs,
    const float* iWq, const float* ibq, const float* iWk, const float* ibk,
    const float* iWv, const float* ibv, const float* iWs,
    float* __restrict__ q, unsigned short* __restrict__ vrow, float* __restrict__ wsk)
{
  __shared__ unsigned short Wt[6*4096];
  __shared__ float bl[6*64];
  __shared__ float wacc[128];
  const float* mats[6]  = {uWq,uWk,uWv,iWq,iWk,iWv};
  const float* bias6[6] = {ubq,ubk,ubv,ibq,ibk,ibv};
  int t = threadIdx.x;
  for (int m=0;m<6;m++)
    for (int e=t; e<4096; e+=256){
      int dd = e>>6, jj = e&63;
      Wt[m*4096 + jj*64 + dd] = f2b(mats[m][e]);
    }
  for (int e=t; e<384; e+=256) bl[e] = bias6[e>>6][e&63];
  if (t<128) wacc[t]=0.f;
  __syncthreads();
  int wave=t>>6, lane=t&63;
  int gw = blockIdx.x*4+wave, nw = gridDim.x*4;
  float accU=0.f, accI=0.f;
  for (int n=gw; n<NTOT; n+=nw){
    int br = (n>=NU);
    const unsigned short* W = Wt + br*3*4096;
    const float* bb = bl + br*192;
    float x = feats[(size_t)n*64+lane];
    float qd=bb[lane], kd=bb[64+lane], vd=bb[128+lane];
    #pragma unroll 16
    for (int j=0;j<64;j++){
      float xj = __shfl(x, j, 64);
      qd += xj * bfu(W[       j*64+lane]);
      kd += xj * bfu(W[4096 + j*64+lane]);
      vd += xj * bfu(W[8192 + j*64+lane]);
    }
    q[(size_t)n*64+lane] = qd;
    vrow[(size_t)n*64+lane] = f2b(vd);
    float wsn = br ? iWs[n-NU] : uWs[n];
    if (br) accI += wsn*kd; else accU += wsn*kd;
  }
  atomicAdd(&wacc[lane], accU);
  atomicAdd(&wacc[64+lane], accI);
  __syncthreads();
  if (t<128) atomicAdd(&wsk[t], wacc[t]);
}

// ---------------- K2: per-slot r quantized to fp8; rfs = dequant, rbs = byte ----------------
__global__ __launch_bounds__(256) void k_score(const float* __restrict__ q, const float* __restrict__ wsk,
    const float* ubs, const float* ibs, float* __restrict__ rfs, unsigned char* __restrict__ rbs)
{
  __shared__ float wl[128];
  int t=threadIdx.x;
  if (t<128) wl[t]=wsk[t];
  __syncthreads();
  int slot = blockIdx.x*256+t;
  if (slot>=KP2) return;
  int n = slot2n(slot);
  if (n<0){ rfs[slot]=0.f; rbs[slot]=0; return; }
  int br = (slot>=8064);
  const float* wk = wl + br*64;
  float s = br ? ibs[0] : ubs[0];
  const float* qr = q + (size_t)n*64;
  #pragma unroll
  for (int d=0;d<64;d++) s += qr[d]*wk[d];
  unsigned char b = f2f8(expf(s));
  rbs[slot] = b;
  rfs[slot] = f8tof<0>((unsigned int)b);
}

// ---------------- K3: ONE pass over H: W8 (G x KP2), W8t (KP2 x G), Z, S2 ----------------
__global__ __launch_bounds__(256) void k_buildW(
    const int* __restrict__ H, const float* __restrict__ rfs, const unsigned char* __restrict__ rbs,
    unsigned char* __restrict__ W8, unsigned char* __restrict__ W8t,
    float* __restrict__ Zu, float* __restrict__ Zi,
    float* __restrict__ S2u, float* __restrict__ S2i)
{
  __shared__ unsigned char Tb[64*68];
  __shared__ float rl[64];
  __shared__ float zp[16][64];
  __shared__ float sp[16][64];
  int t = threadIdx.x;
  int s0 = blockIdx.x*64;
  int g0 = blockIdx.y*64;
  int isItem = (s0 >= 8064);
  if (t < 64) rl[t] = rfs[s0+t];
  __syncthreads();
  int rowb = t >> 4;            // 0..15
  int gq = (t & 15) * 4;        // g-chunk of 4
  float za[4] = {0.f,0.f,0.f,0.f};
  float sa[4] = {0.f,0.f,0.f,0.f};
  #pragma unroll
  for (int i=0;i<4;i++){
    int row = rowb + 16*i;
    int s = s0 + row;
    int n = slot2n(s);
    uchar4 pk; pk.x=0; pk.y=0; pk.z=0; pk.w=0;
    if (n >= 0){
      int4 hv = *(const int4*)(H + (size_t)n*G + g0 + gq);
      unsigned char rb = rbs[s];
      float rq = rl[row];
      if (hv.x){ pk.x=rb; za[0]+=rq; sa[0]+=rq*rq; }
      if (hv.y){ pk.y=rb; za[1]+=rq; sa[1]+=rq*rq; }
      if (hv.z){ pk.z=rb; za[2]+=rq; sa[2]+=rq*rq; }
      if (hv.w){ pk.w=rb; za[3]+=rq; sa[3]+=rq*rq; }
    }
    *(uchar4*)(Tb + row*68 + gq) = pk;
    *(uchar4*)(W8t + (size_t)s*G + g0 + gq) = pk;
  }
  #pragma unroll
  for (int e=0;e<4;e++){ zp[rowb][gq+e]=za[e]; sp[rowb][gq+e]=sa[e]; }
  __syncthreads();
  // W8 transposed write: 4 lanes per g-row, 16 bytes each
  {
    int gl = t >> 2;
    int sc = (t & 3) * 16;
    __align__(16) unsigned char buf[16];
    #pragma unroll
    for (int j=0;j<16;j++) buf[j] = Tb[(sc+j)*68 + gl];
    *(uint4*)(W8 + (size_t)(g0+gl)*KP2 + s0 + sc) = *(uint4*)buf;
  }
  if (t < 64){
    float z=0.f, s2=0.f;
    #pragma unroll
    for (int j=0;j<16;j++){ z += zp[j][t]; s2 += sp[j][t]; }
    if (isItem){ atomicAdd(&Zi[g0+t], z); atomicAdd(&S2i[g0+t], s2); }
    else       { atomicAdd(&Zu[g0+t], z); atomicAdd(&S2u[g0+t], s2); }
  }
}

// ---------------- K4: scales ----------------
__global__ void k_prepC(const float* Zu, const float* Zi, const float* S2u, const float* S2i,
                        float* Cu, float* Ci, float* cnu, float* cni, float* ninv,
                        int* Fu, int* Fi){
  int g = blockIdx.x*256+threadIdx.x;
  if (g>=G) return;
  float zu=Zu[g], zi=Zi[g];
  int fu = !(zu>0.f), fi = !(zi>0.f);
  float cu = fu ? (1.f/(float)NU) : 1.f/zu;   // flagged: W'=1.0 patch -> w = 1/N
  float ci = fi ? (1.f/(float)NI) : 1.f/zi;
  float nu  = fu ? (1.f/(float)NU) : S2u[g]*cu*cu;
  float ni_ = fi ? (1.f/(float)NI) : S2i[g]*ci*ci;
  float nv = rsqrtf(nu+ni_);
  Cu[g]=cu; Ci[g]=ci; ninv[g]=nv; cnu[g]=cu*nv; cni[g]=ci*nv;
  Fu[g]=fu; Fi[g]=fi;
}

// ---------------- K4b: patch all-masked columns with W'=1.0 (fp8 0x38) ----------------
__global__ __launch_bounds__(256) void k_patchF(const int* __restrict__ Fu, const int* __restrict__ Fi,
    unsigned char* __restrict__ W8, unsigned char* __restrict__ W8t){
  int g = blockIdx.x, br = blockIdx.y;
  int flag = br ? Fi[g] : Fu[g];
  if (!flag) return;
  int s0 = br ? 8064 : 0;
  int cnt = br ? NI : NU;
  for (int k = threadIdx.x; k < cnt; k += 256){
    W8[(size_t)g*KP2 + s0 + k] = 0x38;
    W8t[(size_t)(s0+k)*G + g] = 0x38;
  }
}

// ---------------- K5: vt8 (128 x KP2) fp8, v*16, branch-separated, zero-padded ----------------
__global__ __launch_bounds__(256) void k_buildVT(const unsigned short* __restrict__ vrow,
                                                 unsigned char* __restrict__ vt8){
  __shared__ unsigned short tile[64][65];
  int s0 = blockIdx.x*64;
  int tc = threadIdx.x&63, tr = threadIdx.x>>6;
  #pragma unroll
  for (int i=0;i<16;i++){
    int row = tr+i*4;
    int n = slot2n(s0+row);
    tile[row][tc] = (n>=0) ? vrow[(size_t)n*64+tc] : (unsigned short)0;
  }
  __syncthreads();
  int dOff = (s0 >= 8064) ? 64 : 0;
  #pragma unroll
  for (int i=0;i<16;i++){
    int dd = tr+i*4;
    float v = bfu(tile[tc][dd]) * 16.f;
    vt8[(size_t)(dOff+dd)*KP2 + s0+tc] = f2f8(v);
    vt8[(size_t)((dOff^64)+dd)*KP2 + s0+tc] = 0;
  }
}

// ---------------- K6: fp8 GEMM C = A.B^T (k-contig byte rows), 128-elem k-tiles ----------------
// MODE 0: gf = (C_b/16) * (W8 . vt8^T), atomic f32, grid (32,1,16)
// MODE 1: tmpT8 = gfsT2_8 . W8t^T, fp8 out, A-half by J, grid (1,142,1)
// MODE 2: msg = (cn_b/64)*(W8 . tmpT8^T) atomic; deg = cn_b*(W8 . u8) fused, grid (32,1,16)
template<int MODE>
__global__ __launch_bounds__(256) void k_gemm(
    const unsigned char* __restrict__ A, const unsigned char* __restrict__ B,
    float* __restrict__ Cf, unsigned char* __restrict__ C8,
    const float* __restrict__ sU, const float* __restrict__ sI,
    const unsigned char* __restrict__ u8, float* __restrict__ deg,
    long ldA, long ldB, long ldc)
{
  __shared__ __align__(16) unsigned char As[128*128];
  __shared__ __align__(16) unsigned char Bs[128*128];
  int t=threadIdx.x, wave=t>>6, lane=t&63;
  int I=blockIdx.x, J=blockIdx.y, z=blockIdx.z;
  int kt0=0, ktn=0;
  const float* scale = nullptr;
  if (MODE==0){ kt0 = z*9; ktn = min(9, KT8-kt0); }
  else if (MODE==1){ kt0 = 0; ktn = 32; }
  else {
    if (z<8){ kt0 = z*8;             ktn = min(8,  UT8-kt0); scale = sU; }
    else    { kt0 = UT8 + (z-8)*10;  ktn = min(10, KT8-kt0); scale = sI; }
  }
  f32x4 acc[4][4];
  #pragma unroll
  for (int mi=0;mi<4;mi++)
    #pragma unroll
    for (int ni=0;ni<4;ni++){
      acc[mi][ni][0]=0.f; acc[mi][ni][1]=0.f; acc[mi][ni][2]=0.f; acc[mi][ni][3]=0.f;
    }
  f32x4 accd[4];
  if (MODE==2){
    #pragma unroll
    for (int mi=0;mi<4;mi++){ accd[mi][0]=0.f; accd[mi][1]=0.f; accd[mi][2]=0.f; accd[mi][3]=0.f; }
  }
  int l7 = lane&7, q4 = lane>>4, cl15 = lane&15;
  int rowOff = wave*8 + (lane>>3);
  int cchunk = (lane&7) ^ ((lane>>3)&7);
  long aRow0 = (MODE==1) ? ((J>=UT8)?128:0) : (long)I*128;
  const unsigned char* Abase = A + aRow0*ldA + (long)cchunk*16;
  const unsigned char* Bbase = B + (long)J*128*ldB + (long)cchunk*16;
  unsigned char* AsW = As + wave*1024;
  unsigned char* BsW = Bs + wave*1024;
  int mrow0 = (wave&1)*64, nrow0 = (wave>>1)*64;
  for (int kt=kt0; kt<kt0+ktn; ++kt){
    long k0 = (long)kt*128;
    #pragma unroll
    for (int rr=0; rr<4; rr++){
      async16(AsW + rr*4096, Abase + (long)(rr*32 + rowOff)*ldA + k0);
      async16(BsW + rr*4096, Bbase + (long)(rr*32 + rowOff)*ldB + k0);
    }
    __syncthreads();
    #pragma unroll
    for (int kk=0; kk<4; kk++){
      int xoff = (((kk*2 + (q4>>1)) ^ l7) << 4) + ((q4&1)<<3);
      long af[4], bf[4];
      #pragma unroll
      for (int mi=0;mi<4;mi++)
        af[mi] = *(const long*)(As + (mrow0 + mi*16 + cl15)*128 + xoff);
      #pragma unroll
      for (int ni=0;ni<4;ni++)
        bf[ni] = *(const long*)(Bs + (nrow0 + ni*16 + cl15)*128 + xoff);
      #pragma unroll
      for (int mi=0;mi<4;mi++)
        #pragma unroll
        for (int ni=0;ni<4;ni++)
          acc[mi][ni] = __builtin_amdgcn_mfma_f32_16x16x32_fp8_fp8(af[mi], bf[ni], acc[mi][ni], 0,0,0);
      if (MODE==2){
        long bu = 0;
        if (cl15==0) bu = *(const long*)(u8 + (size_t)kt*128 + kk*32 + q4*8);
        #pragma unroll
        for (int mi=0;mi<4;mi++)
          accd[mi] = __builtin_amdgcn_mfma_f32_16x16x32_fp8_fp8(af[mi], bu, accd[mi], 0,0,0);
      }
    }
    __syncthreads();
  }
  int cq = lane>>4, cl = lane&15;
  #pragma unroll
  for (int mi=0;mi<4;mi++)
    #pragma unroll
    for (int ni=0;ni<4;ni++)
      #pragma unroll
      for (int rg=0;rg<4;rg++){
        int gi = (MODE==1 ? 0 : I*128) + mrow0 + mi*16 + cq*4 + rg;
        int hi = J*128 + nrow0 + ni*16 + cl;
        float v = acc[mi][ni][rg];
        if (MODE==0){
          float sc = ((hi & 64) ? sI[gi] : sU[gi]) * 0.0625f;
          atomicAdd(&Cf[(size_t)gi*ldc + hi], v*sc);
        } else if (MODE==1){
          C8[(size_t)gi*ldc + hi] = f2f8(v);
        } else {
          atomicAdd(&Cf[(size_t)gi*ldc + hi], v*scale[gi]*0.015625f);
        }
      }
  if (MODE==2 && cl15==0){
    #pragma unroll
    for (int mi=0;mi<4;mi++)
      #pragma unroll
      for (int rg=0;rg<4;rg++){
        int gi = I*128 + mrow0 + mi*16 + cq*4 + rg;
        atomicAdd(&deg[gi], accd[mi][rg]*scale[gi]);
      }
  }
}

// ---------------- K7: gfsT2_8 (256 x G): rows d = fp8(gf*ninv*Cu*64), 128+d with Ci ----------------
__global__ __launch_bounds__(256) void k_buildGfsT2(const float* __restrict__ gf, const float* __restrict__ ninv,
    const float* __restrict__ Cu, const float* __restrict__ Ci, unsigned char* __restrict__ gfsT2_8){
  __shared__ float tile[64][65];
  int g0 = blockIdx.x*64, d0 = blockIdx.y*64;
  int tc=threadIdx.x&63, tr=threadIdx.x>>6;
  #pragma unroll
  for (int i=0;i<16;i++){
    int rr=tr+i*4;
    tile[rr][tc] = gf[(size_t)(g0+rr)*128 + d0+tc] * ninv[g0+rr];
  }
  __syncthreads();
  #pragma unroll
  for (int i=0;i<16;i++){
    int dd=tr+i*4;
    float v = tile[tc][dd] * 64.f;
    int g = g0+tc;
    gfsT2_8[(size_t)(d0+dd)*G + g]     = f2f8(v*Cu[g]);
    gfsT2_8[(size_t)(128+d0+dd)*G + g] = f2f8(v*Ci[g]);
  }
}

// ---------------- K8: u[k] = sum_g W8[g,k]*cn_b(k)[g] ----------------
__global__ __launch_bounds__(256) void k_u(const unsigned char* __restrict__ W8,
    const float* __restrict__ cnu, const float* __restrict__ cni, float* __restrict__ u){
  long k0 = ((long)blockIdx.x*256 + threadIdx.x)*8;
  if (k0 >= KP2) return;
  int g0 = blockIdx.y*64;
  const float* cn = (k0 < 8064) ? cnu : cni;
  float a[8];
  #pragma unroll
  for (int e=0;e<8;e++) a[e]=0.f;
  for (int j=0;j<64;j++){
    float c = cn[g0+j];
    long w = *(const long*)(W8 + (size_t)(g0+j)*KP2 + k0);
    unsigned int lo = (unsigned int)w, hi = (unsigned int)((unsigned long)w>>32);
    a[0] += f8tof<0>(lo)*c; a[1] += f8tof<1>(lo)*c; a[2] += f8tof<2>(lo)*c; a[3] += f8tof<3>(lo)*c;
    a[4] += f8tof<0>(hi)*c; a[5] += f8tof<1>(hi)*c; a[6] += f8tof<2>(hi)*c; a[7] += f8tof<3>(hi)*c;
  }
  #pragma unroll
  for (int e=0;e<8;e++) atomicAdd(&u[k0+e], a[e]);
}

// ---------------- K8b: u8 = fp8(u) ----------------
__global__ void k_u8(const float* __restrict__ u, unsigned char* __restrict__ u8){
  int k = blockIdx.x*256+threadIdx.x;
  if (k<KP2) u8[k] = f2f8(u[k]);
}

// ---------------- K9: out = sigmoid((0.8 gf + 0.2 msg/deg) @ gW^T + gb) ----------------
__global__ __launch_bounds__(256) void k_final(const float* __restrict__ gf, const float* __restrict__ msg,
    const float* __restrict__ deg, const float* __restrict__ gW, const float* __restrict__ gb,
    float* __restrict__ out)
{
  __shared__ float Wl[64*129];
  __shared__ float aggL[4][128];
  __shared__ float gbL[64];
  int t=threadIdx.x;
  for (int e=t; e<8192; e+=256){ int o=e>>7, dd=e&127; Wl[o*129+dd] = gW[e]; }
  if (t<64) gbL[t] = gb[t];
  int g0 = blockIdx.x*4;
  for (int e=t; e<512; e+=256){
    int gl=e>>7, dd=e&127; int g=g0+gl;
    float dv = deg[g];
    float hn = dv>0.f ? msg[(size_t)g*128+dd]/dv : 0.f;
    aggL[gl][dd] = 0.8f*gf[(size_t)g*128+dd] + 0.2f*hn;
  }
  __syncthreads();
  int gl = t>>6, o = t&63;
  float s = gbL[o];
  #pragma unroll
  for (int dd=0; dd<128; dd++) s += aggL[gl][dd]*Wl[o*129+dd];
  out[(size_t)(g0+gl)*64 + o] = 1.f/(1.f+expf(-s));
}

extern "C" void kernel_launch(void* const* d_in, const int* in_sizes, int n_in,
                              void* d_out, int out_size, void* d_ws, size_t ws_size,
                              hipStream_t stream)
{
  (void)in_sizes; (void)n_in; (void)out_size; (void)ws_size;
  const int* H = (const int*)d_in[0];
  const float* feats = (const float*)d_in[1];
  const float* uWq=(const float*)d_in[3];
  const float* ubq=(const float*)d_in[4];
  const float* uWk=(const float*)d_in[5];
  const float* ubk=(const float*)d_in[6];
  const float* uWv=(const float*)d_in[7];
  const float* ubv=(const float*)d_in[8];
  const float* uWs=(const float*)d_in[9];
  const float* ubs=(const float*)d_in[10];
  const float* iWq=(const float*)d_in[11];
  const float* ibq=(const float*)d_in[12];
  const float* iWk=(const float*)d_in[13];
  const float* ibk=(const float*)d_in[14];
  const float* iWv=(const float*)d_in[15];
  const float* ibv=(const float*)d_in[16];
  const float* iWs=(const float*)d_in[17];
  const float* ibs=(const float*)d_in[18];
  const float* gW =(const float*)d_in[19];
  const float* gb =(const float*)d_in[20];
  float* out = (float*)d_out;

  char* p = (char*)d_ws;
  auto alloc=[&](size_t b)->void*{ void* r=(void*)p; p += (b+255)&~(size_t)255; return r; };
  unsigned char* W8    = (unsigned char*)alloc((size_t)G*KP2);
  unsigned char* W8t   = (unsigned char*)alloc((size_t)KP2*G);
  unsigned char* vt8   = (unsigned char*)alloc((size_t)128*KP2);
  unsigned char* tmpT8 = (unsigned char*)alloc((size_t)128*KP2);
  unsigned char* gfsT2_8=(unsigned char*)alloc((size_t)256*G);
  float* q    = (float*)alloc((size_t)NTOT*64*4);
  unsigned short* vrow=(unsigned short*)alloc((size_t)NTOT*64*2);
  float* rfs  = (float*)alloc((size_t)KP2*4);
  unsigned char* rbs = (unsigned char*)alloc((size_t)KP2);
  float* Zu   = (float*)alloc(G*4);
  float* Zi   = (float*)alloc(G*4);
  float* S2u  = (float*)alloc(G*4);
  float* S2i  = (float*)alloc(G*4);
  float* Cu   = (float*)alloc(G*4);
  float* Ci   = (float*)alloc(G*4);
  float* cnu  = (float*)alloc(G*4);
  float* cni  = (float*)alloc(G*4);
  float* ninv = (float*)alloc(G*4);
  int*   Fu   = (int*)alloc(G*4);
  int*   Fi   = (int*)alloc(G*4);
  float* wsk  = (float*)alloc(128*4);
  float* gf   = (float*)alloc((size_t)G*128*4);
  float* msg  = (float*)alloc((size_t)G*128*4);
  float* u    = (float*)alloc((size_t)KP2*4);
  unsigned char* u8 = (unsigned char*)alloc((size_t)KP2);
  float* deg  = (float*)alloc(G*4);

  (void)hipMemsetAsync(wsk, 0, 128*4, stream);
  (void)hipMemsetAsync(Zu,  0, G*4, stream);
  (void)hipMemsetAsync(Zi,  0, G*4, stream);
  (void)hipMemsetAsync(S2u, 0, G*4, stream);
  (void)hipMemsetAsync(S2i, 0, G*4, stream);
  (void)hipMemsetAsync(gf,  0, (size_t)G*128*4, stream);
  (void)hipMemsetAsync(msg, 0, (size_t)G*128*4, stream);
  (void)hipMemsetAsync(u,   0, (size_t)KP2*4, stream);
  (void)hipMemsetAsync(deg, 0, G*4, stream);

  k_proj<<<128,256,0,stream>>>(feats, uWq,ubq,uWk,ubk,uWv,ubv,uWs,
                               iWq,ibq,iWk,ibk,iWv,ibv,iWs, q, vrow, wsk);
  k_score<<<(KP2+255)/256,256,0,stream>>>(q, wsk, ubs, ibs, rfs, rbs);
  k_buildW<<<dim3(NSL,64),256,0,stream>>>(H, rfs, rbs, W8, W8t, Zu, Zi, S2u, S2i);
  k_prepC<<<16,256,0,stream>>>(Zu,Zi,S2u,S2i,Cu,Ci,cnu,cni,ninv,Fu,Fi);
  k_patchF<<<dim3(G,2),256,0,stream>>>(Fu,Fi,W8,W8t);
  k_buildVT<<<NSL,256,0,stream>>>(vrow, vt8);
  // gf = (C_b/16) * (W8 . vt8^T)
  k_gemm<0><<<dim3(32,1,16),256,0,stream>>>(W8, vt8, gf, nullptr, Cu, Ci, nullptr, nullptr,
                                            (long)KP2, (long)KP2, 128);
  k_buildGfsT2<<<dim3(64,2),256,0,stream>>>(gf, ninv, Cu, Ci, gfsT2_8);
  // tmpT8[d][n] = fp8( sum_g gfsT2_8[d_half,g] * W8t[n,g] )
  k_gemm<1><<<dim3(1,KT8,1),256,0,stream>>>(gfsT2_8, W8t, nullptr, tmpT8, nullptr, nullptr, nullptr, nullptr,
                                            (long)G, (long)G, (long)KP2);
  // u = W8^T cn
  k_u<<<dim3(9,64),256,0,stream>>>(W8, cnu, cni, u);
  k_u8<<<(KP2+255)/256,256,0,stream>>>(u, u8);
  // msg = (cn_b/64) * (W8_b . tmpT8^T), deg fused
  k_gemm<2><<<dim3(32,1,16),256,0,stream>>>(W8, tmpT8, msg, nullptr, cnu, cni, u8, deg,
                                            (long)KP2, (long)KP2, 128);
  k_final<<<G/4,256,0,stream>>>(gf, msg, deg, gW, gb, out);
}

// Round 8
// 815.138 us; speedup vs baseline: 2.1910x; 1.0184x over previous
//
#include <hip/hip_runtime.h>
#include <hip/hip_bf16.h>
#include <cstdint>
#include <cstddef>

#define NU   8000
#define NI   10000
#define NTOT 18000
#define G    4096
#define KP2  18176      // slots: users 0..8063, items 8064..18175
#define NSL  284        // 64-slot tiles
#define NSL128 142      // 128-slot tiles
#define KT8  142        // 128-byte k-tiles
#define UT8  63         // user 128-tiles (63*128 = 8064)

typedef __attribute__((ext_vector_type(4))) float f32x4;

__device__ __forceinline__ float bfu(unsigned short u){
  return __uint_as_float(((unsigned)u)<<16);
}
__device__ __forceinline__ unsigned short f2b(float f){
  __hip_bfloat16 h = __float2bfloat16(f);
  return __builtin_bit_cast(unsigned short, h);
}
__device__ __forceinline__ unsigned char f2f8(float v){
  int p = __builtin_amdgcn_cvt_pk_fp8_f32(v, 0.f, 0, false);
  return (unsigned char)(p & 0xff);
}
template<int SEL>
__device__ __forceinline__ float f8tof(unsigned int w){
  return __builtin_amdgcn_cvt_f32_fp8((int)w, SEL);
}
__device__ __forceinline__ void async16(void* lds, const void* g){
  __builtin_amdgcn_global_load_lds((const __attribute__((address_space(1))) unsigned int*)g,
                                   (__attribute__((address_space(3))) unsigned int*)lds, 16, 0, 0);
}
__device__ __forceinline__ int slot2n(int s){
  return (s < 8064) ? (s < 8000 ? s : -1) : (s-64 < NTOT ? s-64 : -1);
}

// ---------------- K1: q/k/v projections, v rows, wsk = Ws @ k ----------------
__global__ __launch_bounds__(256) void k_proj(
    const float* __restrict__ feats,
    const float* uWq, const float* ubq, const float* uWk, const float* ubk,
    const float* uWv, const float* ubv, const float* uWs,
    const float* iWq, const float* ibq, const float* iWk, const float* ibk,
    const float* iWv, const float* ibv, const float* iWs,
    float* __restrict__ q, unsigned short* __restrict__ vrow, float* __restrict__ wsk)
{
  __shared__ unsigned short Wt[6*4096];
  __shared__ float bl[6*64];
  __shared__ float wacc[128];
  const float* mats[6]  = {uWq,uWk,uWv,iWq,iWk,iWv};
  const float* bias6[6] = {ubq,ubk,ubv,ibq,ibk,ibv};
  int t = threadIdx.x;
  for (int m=0;m<6;m++)
    for (int e=t; e<4096; e+=256){
      int dd = e>>6, jj = e&63;
      Wt[m*4096 + jj*64 + dd] = f2b(mats[m][e]);
    }
  for (int e=t; e<384; e+=256) bl[e] = bias6[e>>6][e&63];
  if (t<128) wacc[t]=0.f;
  __syncthreads();
  int wave=t>>6, lane=t&63;
  int gw = blockIdx.x*4+wave, nw = gridDim.x*4;
  float accU=0.f, accI=0.f;
  for (int n=gw; n<NTOT; n+=nw){
    int br = (n>=NU);
    const unsigned short* W = Wt + br*3*4096;
    const float* bb = bl + br*192;
    float x = feats[(size_t)n*64+lane];
    float qd=bb[lane], kd=bb[64+lane], vd=bb[128+lane];
    #pragma unroll 16
    for (int j=0;j<64;j++){
      float xj = __shfl(x, j, 64);
      qd += xj * bfu(W[       j*64+lane]);
      kd += xj * bfu(W[4096 + j*64+lane]);
      vd += xj * bfu(W[8192 + j*64+lane]);
    }
    q[(size_t)n*64+lane] = qd;
    vrow[(size_t)n*64+lane] = f2b(vd);
    float wsn = br ? iWs[n-NU] : uWs[n];
    if (br) accI += wsn*kd; else accU += wsn*kd;
  }
  atomicAdd(&wacc[lane], accU);
  atomicAdd(&wacc[64+lane], accI);
  __syncthreads();
  if (t<128) atomicAdd(&wsk[t], wacc[t]);
}

// ---------------- K2: per-slot r quantized to fp8; rfs = dequant, rbs = byte ----------------
__global__ __launch_bounds__(256) void k_score(const float* __restrict__ q, const float* __restrict__ wsk,
    const float* ubs, const float* ibs, float* __restrict__ rfs, unsigned char* __restrict__ rbs)
{
  __shared__ float wl[128];
  int t=threadIdx.x;
  if (t<128) wl[t]=wsk[t];
  __syncthreads();
  int slot = blockIdx.x*256+t;
  if (slot>=KP2) return;
  int n = slot2n(slot);
  if (n<0){ rfs[slot]=0.f; rbs[slot]=0; return; }
  int br = (slot>=8064);
  const float* wk = wl + br*64;
  float s = br ? ibs[0] : ubs[0];
  const float* qr = q + (size_t)n*64;
  #pragma unroll
  for (int d=0;d<64;d++) s += qr[d]*wk[d];
  unsigned char b = f2f8(expf(s));
  rbs[slot] = b;
  rfs[slot] = f8tof<0>((unsigned int)b);
}

// ---------------- K3: ONE pass over H, 128x128 tiles: W8, W8t (128B segments), Z, S2 ----------------
// LDS tile stores 16B chunks XOR-swizzled by (row>>3)&7 so the transpose gather avoids bank aliasing.
__global__ __launch_bounds__(256) void k_buildW(
    const int* __restrict__ H, const float* __restrict__ rfs, const unsigned char* __restrict__ rbs,
    unsigned char* __restrict__ W8, unsigned char* __restrict__ W8t,
    float* __restrict__ Zu, float* __restrict__ Zi,
    float* __restrict__ S2u, float* __restrict__ S2i)
{
  __shared__ unsigned char Tb[128*136];
  __shared__ float rl[128];
  __shared__ unsigned char rb[128];
  __shared__ float zp[8][128];
  __shared__ float sp[8][128];
  int t = threadIdx.x;
  int s0 = blockIdx.x*128;      // slot tile (142 tiles, branch-pure: 8064 = 63*128)
  int g0 = blockIdx.y*128;      // g tile (32 tiles)
  int isItem = (s0 >= 8064);
  if (t < 128){
    int n = slot2n(s0+t);
    rl[t] = (n>=0) ? rfs[s0+t] : 0.f;
    rb[t] = (n>=0) ? rbs[s0+t] : (unsigned char)0;
  }
  __syncthreads();
  int rgrp = t>>5;              // 0..7
  int gq   = (t&31)*4;          // g offset 0..124
  int cc   = gq>>4;             // 16B chunk index of gq
  int gi4  = gq&15;
  float za[4]={0.f,0.f,0.f,0.f}, sa[4]={0.f,0.f,0.f,0.f};
  #pragma unroll
  for (int i=0;i<16;i++){
    int row = i*8 + rgrp;
    int n = slot2n(s0+row);
    uchar4 pk; pk.x=0; pk.y=0; pk.z=0; pk.w=0;
    if (n >= 0){
      int4 hv = *(const int4*)(H + (size_t)n*G + g0 + gq);
      unsigned char rbv = rb[row];
      float rq = rl[row];
      if (hv.x){ pk.x=rbv; za[0]+=rq; sa[0]+=rq*rq; }
      if (hv.y){ pk.y=rbv; za[1]+=rq; sa[1]+=rq*rq; }
      if (hv.z){ pk.z=rbv; za[2]+=rq; sa[2]+=rq*rq; }
      if (hv.w){ pk.w=rbv; za[3]+=rq; sa[3]+=rq*rq; }
    }
    int scc = cc ^ ((row>>3)&7);     // swizzled chunk
    *(uchar4*)(Tb + row*136 + (scc<<4) + gi4) = pk;
  }
  #pragma unroll
  for (int e=0;e<4;e++){ zp[rgrp][gq+e]=za[e]; sp[rgrp][gq+e]=sa[e]; }
  __syncthreads();
  // W8t: row = slot, 128 B per row via 8 lanes x uint4 (LDS read is vectorized b128)
  #pragma unroll
  for (int p=0;p<4;p++){
    int row = p*32 + (t>>3);
    int c   = t&7;
    int scc = c ^ ((row>>3)&7);
    uint4 v = *(const uint4*)(Tb + row*136 + (scc<<4));
    *(uint4*)(W8t + (size_t)(s0+row)*G + g0 + (c<<4)) = v;
  }
  // W8: row = g, 128 slots = 128 B; byte transpose gather from swizzled tile
  #pragma unroll
  for (int p=0;p<4;p++){
    int gl = p*32 + (t>>3);          // g-local
    int sc = (t&7)*16;               // slot chunk base
    int gcc = gl>>4, gb = gl&15;
    __align__(16) unsigned char buf[16];
    #pragma unroll
    for (int j=0;j<16;j++){
      int row = sc+j;
      int scc = gcc ^ ((row>>3)&7);
      buf[j] = Tb[row*136 + (scc<<4) + gb];
    }
    *(uint4*)(W8 + (size_t)(g0+gl)*KP2 + s0 + sc) = *(uint4*)buf;
  }
  if (t < 128){
    float z=0.f, s2=0.f;
    #pragma unroll
    for (int j=0;j<8;j++){ z += zp[j][t]; s2 += sp[j][t]; }
    if (isItem){ atomicAdd(&Zi[g0+t], z); atomicAdd(&S2i[g0+t], s2); }
    else       { atomicAdd(&Zu[g0+t], z); atomicAdd(&S2u[g0+t], s2); }
  }
}

// ---------------- K4: scales ----------------
__global__ void k_prepC(const float* Zu, const float* Zi, const float* S2u, const float* S2i,
                        float* Cu, float* Ci, float* cnu, float* cni, float* ninv,
                        int* Fu, int* Fi){
  int g = blockIdx.x*256+threadIdx.x;
  if (g>=G) return;
  float zu=Zu[g], zi=Zi[g];
  int fu = !(zu>0.f), fi = !(zi>0.f);
  float cu = fu ? (1.f/(float)NU) : 1.f/zu;   // flagged: W'=1.0 patch -> w = 1/N
  float ci = fi ? (1.f/(float)NI) : 1.f/zi;
  float nu  = fu ? (1.f/(float)NU) : S2u[g]*cu*cu;
  float ni_ = fi ? (1.f/(float)NI) : S2i[g]*ci*ci;
  float nv = rsqrtf(nu+ni_);
  Cu[g]=cu; Ci[g]=ci; ninv[g]=nv; cnu[g]=cu*nv; cni[g]=ci*nv;
  Fu[g]=fu; Fi[g]=fi;
}

// ---------------- K4b: patch all-masked columns with W'=1.0 (fp8 0x38) ----------------
__global__ __launch_bounds__(256) void k_patchF(const int* __restrict__ Fu, const int* __restrict__ Fi,
    unsigned char* __restrict__ W8, unsigned char* __restrict__ W8t){
  int g = blockIdx.x, br = blockIdx.y;
  int flag = br ? Fi[g] : Fu[g];
  if (!flag) return;
  int s0 = br ? 8064 : 0;
  int cnt = br ? NI : NU;
  for (int k = threadIdx.x; k < cnt; k += 256){
    W8[(size_t)g*KP2 + s0 + k] = 0x38;
    W8t[(size_t)(s0+k)*G + g] = 0x38;
  }
}

// ---------------- K5: vt8 (128 x KP2) fp8, v*16, branch-separated, zero-padded ----------------
__global__ __launch_bounds__(256) void k_buildVT(const unsigned short* __restrict__ vrow,
                                                 unsigned char* __restrict__ vt8){
  __shared__ unsigned short tile[64][65];
  int s0 = blockIdx.x*64;
  int tc = threadIdx.x&63, tr = threadIdx.x>>6;
  #pragma unroll
  for (int i=0;i<16;i++){
    int row = tr+i*4;
    int n = slot2n(s0+row);
    tile[row][tc] = (n>=0) ? vrow[(size_t)n*64+tc] : (unsigned short)0;
  }
  __syncthreads();
  int dOff = (s0 >= 8064) ? 64 : 0;
  #pragma unroll
  for (int i=0;i<16;i++){
    int dd = tr+i*4;
    float v = bfu(tile[tc][dd]) * 16.f;
    vt8[(size_t)(dOff+dd)*KP2 + s0+tc] = f2f8(v);
    vt8[(size_t)((dOff^64)+dd)*KP2 + s0+tc] = 0;
  }
}

// ---------------- K6: fp8 GEMM C = A.B^T (k-contig byte rows), 128-elem k-tiles ----------------
// MODE 0: gf = (C_b/16) * (W8 . vt8^T), atomic f32, grid (32,1,16)
// MODE 1: tmpT8 = gfsT2_8 . W8t^T, fp8 out, A-half by J, grid (1,142,1)
// MODE 2: msg = (cn_b/64)*(W8 . tmpT8^T) atomic; deg = cn_b*(W8 . u8) fused, grid (32,1,16)
template<int MODE>
__global__ __launch_bounds__(256) void k_gemm(
    const unsigned char* __restrict__ A, const unsigned char* __restrict__ B,
    float* __restrict__ Cf, unsigned char* __restrict__ C8,
    const float* __restrict__ sU, const float* __restrict__ sI,
    const unsigned char* __restrict__ u8, float* __restrict__ deg,
    long ldA, long ldB, long ldc)
{
  __shared__ __align__(16) unsigned char As[128*128];
  __shared__ __align__(16) unsigned char Bs[128*128];
  int t=threadIdx.x, wave=t>>6, lane=t&63;
  int I=blockIdx.x, J=blockIdx.y, z=blockIdx.z;
  int kt0=0, ktn=0;
  const float* scale = nullptr;
  if (MODE==0){ kt0 = z*9; ktn = min(9, KT8-kt0); }
  else if (MODE==1){ kt0 = 0; ktn = 32; }
  else {
    if (z<8){ kt0 = z*8;             ktn = min(8,  UT8-kt0); scale = sU; }
    else    { kt0 = UT8 + (z-8)*10;  ktn = min(10, KT8-kt0); scale = sI; }
  }
  f32x4 acc[4][4];
  #pragma unroll
  for (int mi=0;mi<4;mi++)
    #pragma unroll
    for (int ni=0;ni<4;ni++){
      acc[mi][ni][0]=0.f; acc[mi][ni][1]=0.f; acc[mi][ni][2]=0.f; acc[mi][ni][3]=0.f;
    }
  f32x4 accd[4];
  if (MODE==2){
    #pragma unroll
    for (int mi=0;mi<4;mi++){ accd[mi][0]=0.f; accd[mi][1]=0.f; accd[mi][2]=0.f; accd[mi][3]=0.f; }
  }
  int l7 = lane&7, q4 = lane>>4, cl15 = lane&15;
  int rowOff = wave*8 + (lane>>3);
  int cchunk = (lane&7) ^ ((lane>>3)&7);
  long aRow0 = (MODE==1) ? ((J>=UT8)?128:0) : (long)I*128;
  const unsigned char* Abase = A + aRow0*ldA + (long)cchunk*16;
  const unsigned char* Bbase = B + (long)J*128*ldB + (long)cchunk*16;
  unsigned char* AsW = As + wave*1024;
  unsigned char* BsW = Bs + wave*1024;
  int mrow0 = (wave&1)*64, nrow0 = (wave>>1)*64;
  for (int kt=kt0; kt<kt0+ktn; ++kt){
    long k0 = (long)kt*128;
    #pragma unroll
    for (int rr=0; rr<4; rr++){
      async16(AsW + rr*4096, Abase + (long)(rr*32 + rowOff)*ldA + k0);
      async16(BsW + rr*4096, Bbase + (long)(rr*32 + rowOff)*ldB + k0);
    }
    __syncthreads();
    #pragma unroll
    for (int kk=0; kk<4; kk++){
      int xoff = (((kk*2 + (q4>>1)) ^ l7) << 4) + ((q4&1)<<3);
      long af[4], bf[4];
      #pragma unroll
      for (int mi=0;mi<4;mi++)
        af[mi] = *(const long*)(As + (mrow0 + mi*16 + cl15)*128 + xoff);
      #pragma unroll
      for (int ni=0;ni<4;ni++)
        bf[ni] = *(const long*)(Bs + (nrow0 + ni*16 + cl15)*128 + xoff);
      #pragma unroll
      for (int mi=0;mi<4;mi++)
        #pragma unroll
        for (int ni=0;ni<4;ni++)
          acc[mi][ni] = __builtin_amdgcn_mfma_f32_16x16x32_fp8_fp8(af[mi], bf[ni], acc[mi][ni], 0,0,0);
      if (MODE==2){
        long bu = 0;
        if (cl15==0) bu = *(const long*)(u8 + (size_t)kt*128 + kk*32 + q4*8);
        #pragma unroll
        for (int mi=0;mi<4;mi++)
          accd[mi] = __builtin_amdgcn_mfma_f32_16x16x32_fp8_fp8(af[mi], bu, accd[mi], 0,0,0);
      }
    }
    __syncthreads();
  }
  int cq = lane>>4, cl = lane&15;
  #pragma unroll
  for (int mi=0;mi<4;mi++)
    #pragma unroll
    for (int ni=0;ni<4;ni++)
      #pragma unroll
      for (int rg=0;rg<4;rg++){
        int gi = (MODE==1 ? 0 : I*128) + mrow0 + mi*16 + cq*4 + rg;
        int hi = J*128 + nrow0 + ni*16 + cl;
        float v = acc[mi][ni][rg];
        if (MODE==0){
          float sc = ((hi & 64) ? sI[gi] : sU[gi]) * 0.0625f;
          atomicAdd(&Cf[(size_t)gi*ldc + hi], v*sc);
        } else if (MODE==1){
          C8[(size_t)gi*ldc + hi] = f2f8(v);
        } else {
          atomicAdd(&Cf[(size_t)gi*ldc + hi], v*scale[gi]*0.015625f);
        }
      }
  if (MODE==2 && cl15==0){
    #pragma unroll
    for (int mi=0;mi<4;mi++)
      #pragma unroll
      for (int rg=0;rg<4;rg++){
        int gi = I*128 + mrow0 + mi*16 + cq*4 + rg;
        atomicAdd(&deg[gi], accd[mi][rg]*scale[gi]);
      }
  }
}

// ---------------- K7: gfsT2_8 (256 x G): rows d = fp8(gf*ninv*Cu*64), 128+d with Ci ----------------
__global__ __launch_bounds__(256) void k_buildGfsT2(const float* __restrict__ gf, const float* __restrict__ ninv,
    const float* __restrict__ Cu, const float* __restrict__ Ci, unsigned char* __restrict__ gfsT2_8){
  __shared__ float tile[64][65];
  int g0 = blockIdx.x*64, d0 = blockIdx.y*64;
  int tc=threadIdx.x&63, tr=threadIdx.x>>6;
  #pragma unroll
  for (int i=0;i<16;i++){
    int rr=tr+i*4;
    tile[rr][tc] = gf[(size_t)(g0+rr)*128 + d0+tc] * ninv[g0+rr];
  }
  __syncthreads();
  #pragma unroll
  for (int i=0;i<16;i++){
    int dd=tr+i*4;
    float v = tile[tc][dd] * 64.f;
    int g = g0+tc;
    gfsT2_8[(size_t)(d0+dd)*G + g]     = f2f8(v*Cu[g]);
    gfsT2_8[(size_t)(128+d0+dd)*G + g] = f2f8(v*Ci[g]);
  }
}

// ---------------- K8: u[k] = sum_g W8[g,k]*cn_b(k)[g] ----------------
__global__ __launch_bounds__(256) void k_u(const unsigned char* __restrict__ W8,
    const float* __restrict__ cnu, const float* __restrict__ cni, float* __restrict__ u){
  long k0 = ((long)blockIdx.x*256 + threadIdx.x)*8;
  if (k0 >= KP2) return;
  int g0 = blockIdx.y*64;
  const float* cn = (k0 < 8064) ? cnu : cni;
  float a[8];
  #pragma unroll
  for (int e=0;e<8;e++) a[e]=0.f;
  for (int j=0;j<64;j++){
    float c = cn[g0+j];
    long w = *(const long*)(W8 + (size_t)(g0+j)*KP2 + k0);
    unsigned int lo = (unsigned int)w, hi = (unsigned int)((unsigned long)w>>32);
    a[0] += f8tof<0>(lo)*c; a[1] += f8tof<1>(lo)*c; a[2] += f8tof<2>(lo)*c; a[3] += f8tof<3>(lo)*c;
    a[4] += f8tof<0>(hi)*c; a[5] += f8tof<1>(hi)*c; a[6] += f8tof<2>(hi)*c; a[7] += f8tof<3>(hi)*c;
  }
  #pragma unroll
  for (int e=0;e<8;e++) atomicAdd(&u[k0+e], a[e]);
}

// ---------------- K8b: u8 = fp8(u) ----------------
__global__ void k_u8(const float* __restrict__ u, unsigned char* __restrict__ u8){
  int k = blockIdx.x*256+threadIdx.x;
  if (k<KP2) u8[k] = f2f8(u[k]);
}

// ---------------- K9: out = sigmoid((0.8 gf + 0.2 msg/deg) @ gW^T + gb) ----------------
__global__ __launch_bounds__(256) void k_final(const float* __restrict__ gf, const float* __restrict__ msg,
    const float* __restrict__ deg, const float* __restrict__ gW, const float* __restrict__ gb,
    float* __restrict__ out)
{
  __shared__ float Wl[64*129];
  __shared__ float aggL[4][128];
  __shared__ float gbL[64];
  int t=threadIdx.x;
  for (int e=t; e<8192; e+=256){ int o=e>>7, dd=e&127; Wl[o*129+dd] = gW[e]; }
  if (t<64) gbL[t] = gb[t];
  int g0 = blockIdx.x*4;
  for (int e=t; e<512; e+=256){
    int gl=e>>7, dd=e&127; int g=g0+gl;
    float dv = deg[g];
    float hn = dv>0.f ? msg[(size_t)g*128+dd]/dv : 0.f;
    aggL[gl][dd] = 0.8f*gf[(size_t)g*128+dd] + 0.2f*hn;
  }
  __syncthreads();
  int gl = t>>6, o = t&63;
  float s = gbL[o];
  #pragma unroll
  for (int dd=0; dd<128; dd++) s += aggL[gl][dd]*Wl[o*129+dd];
  out[(size_t)(g0+gl)*64 + o] = 1.f/(1.f+expf(-s));
}

extern "C" void kernel_launch(void* const* d_in, const int* in_sizes, int n_in,
                              void* d_out, int out_size, void* d_ws, size_t ws_size,
                              hipStream_t stream)
{
  (void)in_sizes; (void)n_in; (void)out_size; (void)ws_size;
  const int* H = (const int*)d_in[0];
  const float* feats = (const float*)d_in[1];
  const float* uWq=(const float*)d_in[3];
  const float* ubq=(const float*)d_in[4];
  const float* uWk=(const float*)d_in[5];
  const float* ubk=(const float*)d_in[6];
  const float* uWv=(const float*)d_in[7];
  const float* ubv=(const float*)d_in[8];
  const float* uWs=(const float*)d_in[9];
  const float* ubs=(const float*)d_in[10];
  const float* iWq=(const float*)d_in[11];
  const float* ibq=(const float*)d_in[12];
  const float* iWk=(const float*)d_in[13];
  const float* ibk=(const float*)d_in[14];
  const float* iWv=(const float*)d_in[15];
  const float* ibv=(const float*)d_in[16];
  const float* iWs=(const float*)d_in[17];
  const float* ibs=(const float*)d_in[18];
  const float* gW =(const float*)d_in[19];
  const float* gb =(const float*)d_in[20];
  float* out = (float*)d_out;

  char* p = (char*)d_ws;
  auto alloc=[&](size_t b)->void*{ void* r=(void*)p; p += (b+255)&~(size_t)255; return r; };
  unsigned char* W8    = (unsigned char*)alloc((size_t)G*KP2);
  unsigned char* W8t   = (unsigned char*)alloc((size_t)KP2*G);
  unsigned char* vt8   = (unsigned char*)alloc((size_t)128*KP2);
  unsigned char* tmpT8 = (unsigned char*)alloc((size_t)128*KP2);
  unsigned char* gfsT2_8=(unsigned char*)alloc((size_t)256*G);
  float* q    = (float*)alloc((size_t)NTOT*64*4);
  unsigned short* vrow=(unsigned short*)alloc((size_t)NTOT*64*2);
  float* rfs  = (float*)alloc((size_t)KP2*4);
  unsigned char* rbs = (unsigned char*)alloc((size_t)KP2);
  float* Zu   = (float*)alloc(G*4);
  float* Zi   = (float*)alloc(G*4);
  float* S2u  = (float*)alloc(G*4);
  float* S2i  = (float*)alloc(G*4);
  float* Cu   = (float*)alloc(G*4);
  float* Ci   = (float*)alloc(G*4);
  float* cnu  = (float*)alloc(G*4);
  float* cni  = (float*)alloc(G*4);
  float* ninv = (float*)alloc(G*4);
  int*   Fu   = (int*)alloc(G*4);
  int*   Fi   = (int*)alloc(G*4);
  float* wsk  = (float*)alloc(128*4);
  float* gf   = (float*)alloc((size_t)G*128*4);
  float* msg  = (float*)alloc((size_t)G*128*4);
  float* u    = (float*)alloc((size_t)KP2*4);
  unsigned char* u8 = (unsigned char*)alloc((size_t)KP2);
  float* deg  = (float*)alloc(G*4);

  (void)hipMemsetAsync(wsk, 0, 128*4, stream);
  (void)hipMemsetAsync(Zu,  0, G*4, stream);
  (void)hipMemsetAsync(Zi,  0, G*4, stream);
  (void)hipMemsetAsync(S2u, 0, G*4, stream);
  (void)hipMemsetAsync(S2i, 0, G*4, stream);
  (void)hipMemsetAsync(gf,  0, (size_t)G*128*4, stream);
  (void)hipMemsetAsync(msg, 0, (size_t)G*128*4, stream);
  (void)hipMemsetAsync(u,   0, (size_t)KP2*4, stream);
  (void)hipMemsetAsync(deg, 0, G*4, stream);

  k_proj<<<128,256,0,stream>>>(feats, uWq,ubq,uWk,ubk,uWv,ubv,uWs,
                               iWq,ibq,iWk,ibk,iWv,ibv,iWs, q, vrow, wsk);
  k_score<<<(KP2+255)/256,256,0,stream>>>(q, wsk, ubs, ibs, rfs, rbs);
  k_buildW<<<dim3(NSL128,32),256,0,stream>>>(H, rfs, rbs, W8, W8t, Zu, Zi, S2u, S2i);
  k_prepC<<<16,256,0,stream>>>(Zu,Zi,S2u,S2i,Cu,Ci,cnu,cni,ninv,Fu,Fi);
  k_patchF<<<dim3(G,2),256,0,stream>>>(Fu,Fi,W8,W8t);
  k_buildVT<<<NSL,256,0,stream>>>(vrow, vt8);
  // gf = (C_b/16) * (W8 . vt8^T)
  k_gemm<0><<<dim3(32,1,16),256,0,stream>>>(W8, vt8, gf, nullptr, Cu, Ci, nullptr, nullptr,
                                            (long)KP2, (long)KP2, 128);
  k_buildGfsT2<<<dim3(64,2),256,0,stream>>>(gf, ninv, Cu, Ci, gfsT2_8);
  // tmpT8[d][n] = fp8( sum_g gfsT2_8[d_half,g] * W8t[n,g] )
  k_gemm<1><<<dim3(1,KT8,1),256,0,stream>>>(gfsT2_8, W8t, nullptr, tmpT8, nullptr, nullptr, nullptr, nullptr,
                                            (long)G, (long)G, (long)KP2);
  // u = W8^T cn
  k_u<<<dim3(9,64),256,0,stream>>>(W8, cnu, cni, u);
  k_u8<<<(KP2+255)/256,256,0,stream>>>(u, u8);
  // msg = (cn_b/64) * (W8_b . tmpT8^T), deg fused
  k_gemm<2><<<dim3(32,1,16),256,0,stream>>>(W8, tmpT8, msg, nullptr, cnu, cni, u8, deg,
                                            (long)KP2, (long)KP2, 128);
  k_final<<<G/4,256,0,stream>>>(gf, msg, deg, gW, gb, out);
}